// Round 7
// baseline (2949.173 us; speedup 1.0000x reference)
//
#include <hip/hip_runtime.h>
#include <math.h>

#define NN 50000
#define EE 800000
#define DD 96
#define NHID 128
#define NOUT 8
#define LDA 104   // padded LDS row stride in bf16 elems (208 B; 16B-aligned)

typedef unsigned int uint32;
typedef float floatx2 __attribute__((ext_vector_type(2)));
typedef float f32x4 __attribute__((ext_vector_type(4)));
typedef short bf16x8 __attribute__((ext_vector_type(8)));
typedef ushort ushort8_t __attribute__((ext_vector_type(8)));

__device__ __forceinline__ float bfu2f(ushort u) {
  union { uint32 u; float f; } v; v.u = ((uint32)u) << 16; return v.f;
}
__device__ __forceinline__ ushort f2bf(float x) {
  union { float f; uint32 u; } v; v.f = x;
  uint32 r = (v.u + 0x7fffu + ((v.u >> 16) & 1u)) >> 16;
  return (ushort)r;
}

// Edge storage traits: 2 -> bf16, 1 -> fp8 e4m3 (OCP, HW cvt).
// ld/st: group-of-4-channels index. ld8/st8: group-of-8-channels index.
template <int ESZ> struct EST;
template <> struct EST<2> {
  static __device__ __forceinline__ float4 ld(const void* e, size_t grp) {
    const ushort4 a = ((const ushort4*)e)[grp];
    return make_float4(bfu2f(a.x), bfu2f(a.y), bfu2f(a.z), bfu2f(a.w));
  }
  static __device__ __forceinline__ void st(void* e, size_t grp, float4 v) {
    ushort4 o; o.x = f2bf(v.x); o.y = f2bf(v.y); o.z = f2bf(v.z); o.w = f2bf(v.w);
    ((ushort4*)e)[grp] = o;
  }
  static __device__ __forceinline__ void ld8(const void* e, size_t i8, float* a) {
    const ushort8_t u = ((const ushort8_t*)e)[i8];
#pragma unroll
    for (int j = 0; j < 8; j++) a[j] = bfu2f(u[j]);
  }
  static __device__ __forceinline__ void st8(void* e, size_t i8, const float* a) {
    ushort8_t u;
#pragma unroll
    for (int j = 0; j < 8; j++) u[j] = f2bf(a[j]);
    ((ushort8_t*)e)[i8] = u;
  }
  static __device__ __forceinline__ float ld1c(const void* e, size_t pos, int c) {
    return bfu2f(((const ushort*)e)[pos * DD + c]);
  }
};
template <> struct EST<1> {
  static __device__ __forceinline__ float4 ld(const void* e, size_t grp) {
    const int u = ((const int*)e)[grp];
    floatx2 lo = __builtin_amdgcn_cvt_pk_f32_fp8(u, false);
    floatx2 hi = __builtin_amdgcn_cvt_pk_f32_fp8(u, true);
    return make_float4(lo[0], lo[1], hi[0], hi[1]);
  }
  static __device__ __forceinline__ void st(void* e, size_t grp, float4 v) {
    int u = 0;
    u = __builtin_amdgcn_cvt_pk_fp8_f32(v.x, v.y, u, false);
    u = __builtin_amdgcn_cvt_pk_fp8_f32(v.z, v.w, u, true);
    ((int*)e)[grp] = u;
  }
  static __device__ __forceinline__ void ld8(const void* e, size_t i8, float* a) {
    const int2 u = ((const int2*)e)[i8];
    floatx2 l0 = __builtin_amdgcn_cvt_pk_f32_fp8(u.x, false);
    floatx2 h0 = __builtin_amdgcn_cvt_pk_f32_fp8(u.x, true);
    floatx2 l1 = __builtin_amdgcn_cvt_pk_f32_fp8(u.y, false);
    floatx2 h1 = __builtin_amdgcn_cvt_pk_f32_fp8(u.y, true);
    a[0]=l0[0]; a[1]=l0[1]; a[2]=h0[0]; a[3]=h0[1];
    a[4]=l1[0]; a[5]=l1[1]; a[6]=h1[0]; a[7]=h1[1];
  }
  static __device__ __forceinline__ void st8(void* e, size_t i8, const float* a) {
    int2 u;
    int w0 = 0;
    w0 = __builtin_amdgcn_cvt_pk_fp8_f32(a[0], a[1], w0, false);
    w0 = __builtin_amdgcn_cvt_pk_fp8_f32(a[2], a[3], w0, true);
    int w1 = 0;
    w1 = __builtin_amdgcn_cvt_pk_fp8_f32(a[4], a[5], w1, false);
    w1 = __builtin_amdgcn_cvt_pk_fp8_f32(a[6], a[7], w1, true);
    u.x = w0; u.y = w1;
    ((int2*)e)[i8] = u;
  }
  static __device__ __forceinline__ float ld1c(const void* e, size_t pos, int c) {
    const int dw = ((const int*)e)[pos * (DD / 4) + (c >> 2)];
    floatx2 lo = __builtin_amdgcn_cvt_pk_f32_fp8(dw, false);
    floatx2 hi = __builtin_amdgcn_cvt_pk_f32_fp8(dw, true);
    return (c & 2) ? ((c & 1) ? hi[1] : hi[0]) : ((c & 1) ? lo[1] : lo[0]);
  }
};

// ------------------------------------------------------------- init / CSR build
__global__ __launch_bounds__(256) void k_zero_init(int* __restrict__ cnt,
    float* __restrict__ stats) {
  int i = blockIdx.x * 256 + threadIdx.x;
  const int str = gridDim.x * 256;
  for (; i < NN; i += str) cnt[i] = 0;
  if (blockIdx.x == 0)
    for (int j = threadIdx.x; j < 768; j += 256) stats[j] = 0.f;
}

__global__ __launch_bounds__(256) void k_hist(const int* __restrict__ dst,
    int* __restrict__ cnt) {
  const int i = blockIdx.x * 256 + threadIdx.x;
  if (i < EE) atomicAdd(&cnt[dst[i]], 1);
}

__global__ __launch_bounds__(256) void k_scan(const int* __restrict__ cnt,
    int* __restrict__ rowptr, int* __restrict__ cursor) {
  __shared__ int part[256];
  const int t = threadIdx.x;
  const int CH = (NN + 255) / 256;
  const int lo = t * CH, hi = min((t + 1) * CH, NN);
  int s = 0;
  for (int i = lo; i < hi; i++) s += cnt[i];
  part[t] = s;
  __syncthreads();
  for (int off = 1; off < 256; off <<= 1) {
    int v = (t >= off) ? part[t - off] : 0;
    __syncthreads();
    part[t] += v;
    __syncthreads();
  }
  int base = (t == 0) ? 0 : part[t - 1];
  for (int i = lo; i < hi; i++) {
    rowptr[i] = base; cursor[i] = base; base += cnt[i];
  }
  if (t == 255) rowptr[NN] = base;
}

__global__ __launch_bounds__(256) void k_scatter(const int* __restrict__ src,
    const int* __restrict__ dst, int* __restrict__ cursor,
    int* __restrict__ perm, int* __restrict__ srcC, int* __restrict__ dstC) {
  const int i = blockIdx.x * 256 + threadIdx.x;
  if (i < EE) {
    const int d = dst[i];
    const int pos = atomicAdd(&cursor[d], 1);
    perm[pos] = i; srcC[pos] = src[i]; dstC[pos] = d;
  }
}

// ---------------------------------------------------------------- embeddings
__global__ __launch_bounds__(256) void k_embed_h(const float* __restrict__ h1,
    const float* __restrict__ h2, const float* __restrict__ z,
    const float* __restrict__ W, const float* __restrict__ b,
    ushort* __restrict__ h) {
  int idx = blockIdx.x * 256 + threadIdx.x;
  const int total = NN * DD;
  const int stride = gridDim.x * 256;
  for (; idx < total; idx += stride) {
    int n = idx / DD, c = idx - n * DD;
    float acc = b[c];
#pragma unroll
    for (int k = 0; k < 6; k++)  acc = fmaf(h1[n * 6 + k], W[k * DD + c], acc);
#pragma unroll
    for (int k = 0; k < 4; k++)  acc = fmaf(h2[n * 4 + k], W[(6 + k) * DD + c], acc);
#pragma unroll
    for (int k = 0; k < 16; k++) acc = fmaf(z[n * 16 + k], W[(10 + k) * DD + c], acc);
    h[idx] = f2bf(acc);
  }
}

template <int EZ>
__global__ __launch_bounds__(256) void k_embed_e(const float* __restrict__ ef,
    const float* __restrict__ W, const float* __restrict__ b,
    const int* __restrict__ perm, void* __restrict__ e) {
  int g = blockIdx.x * 256 + threadIdx.x;
  const int totalg = EE * (DD / 4);
  const int stride = gridDim.x * 256;
  for (; g < totalg; g += stride) {
    const int pos = g / 24, cg = (g - pos * 24) * 4;
    const int orig = perm[pos];
    const float f0 = ef[orig * 4], f1 = ef[orig * 4 + 1];
    const float f2 = ef[orig * 4 + 2], f3 = ef[orig * 4 + 3];
    float4 acc;
    acc.x = b[cg+0] + f0*W[cg+0] + f1*W[DD+cg+0] + f2*W[2*DD+cg+0] + f3*W[3*DD+cg+0];
    acc.y = b[cg+1] + f0*W[cg+1] + f1*W[DD+cg+1] + f2*W[2*DD+cg+1] + f3*W[3*DD+cg+1];
    acc.z = b[cg+2] + f0*W[cg+2] + f1*W[DD+cg+2] + f2*W[2*DD+cg+2] + f3*W[3*DD+cg+2];
    acc.w = b[cg+3] + f0*W[cg+3] + f1*W[DD+cg+3] + f2*W[2*DD+cg+3] + f3*W[3*DD+cg+3];
    EST<EZ>::st(e, g, acc);
  }
}

// ------------------------------------- node GEMMs via MFMA (A,B,D,E by blockIdx.y)
__global__ __launch_bounds__(256) void k_ngemm(const ushort* __restrict__ h,
    const float* __restrict__ WAp, const float* __restrict__ WBp,
    const float* __restrict__ WDp, const float* __restrict__ WEp,
    const float* __restrict__ bAp, const float* __restrict__ bBp,
    const float* __restrict__ bDp, const float* __restrict__ bEp,
    ushort* __restrict__ oA, ushort* __restrict__ oB,
    ushort* __restrict__ oD, ushort* __restrict__ oE) {
  const float* W; const float* bias; ushort* out;
  const int m = blockIdx.y;
  if (m == 0)      { W = WAp; bias = bAp; out = oA; }
  else if (m == 1) { W = WBp; bias = bBp; out = oB; }
  else if (m == 2) { W = WDp; bias = bDp; out = oD; }
  else             { W = WEp; bias = bEp; out = oE; }
  __shared__ __align__(16) ushort Wt[DD * LDA];
  __shared__ __align__(16) ushort At[64 * LDA];
  const int tid = threadIdx.x;
  for (int i = tid; i < DD * DD; i += 256) {
    const int k = i / DD, n = i - (i / DD) * DD;
    Wt[n * LDA + k] = f2bf(W[i]);
  }
  const int base = blockIdx.x * 64;
  for (int i = tid; i < 64 * 24; i += 256) {
    const int r = i / 24, q = i - (i / 24) * 24;
    const int row = base + r;
    ushort4 a;
    if (row < NN) a = ((const ushort4*)h)[(size_t)row * 24 + q];
    else { a.x = 0; a.y = 0; a.z = 0; a.w = 0; }
    *(ushort4*)&At[r * LDA + q * 4] = a;
  }
  __syncthreads();
  const int w = tid >> 6, lane = tid & 63;
  const int lrow = lane & 15, lgrp = lane >> 4;
  f32x4 acc[6];
#pragma unroll
  for (int nt = 0; nt < 6; nt++) { acc[nt][0]=0.f; acc[nt][1]=0.f; acc[nt][2]=0.f; acc[nt][3]=0.f; }
#pragma unroll
  for (int kk = 0; kk < 3; kk++) {
    const bf16x8 af = *(const bf16x8*)&At[(w * 16 + lrow) * LDA + kk * 32 + lgrp * 8];
#pragma unroll
    for (int nt = 0; nt < 6; nt++) {
      const bf16x8 bfr = *(const bf16x8*)&Wt[(nt * 16 + lrow) * LDA + kk * 32 + lgrp * 8];
      acc[nt] = __builtin_amdgcn_mfma_f32_16x16x32_bf16(af, bfr, acc[nt], 0, 0, 0);
    }
  }
#pragma unroll
  for (int j = 0; j < 4; j++) {
    const int row = base + w * 16 + lgrp * 4 + j;
    if (row < NN) {
#pragma unroll
      for (int nt = 0; nt < 6; nt++) {
        const int ch = nt * 16 + lrow;
        out[(size_t)row * DD + ch] = f2bf(acc[nt][j] + bias[ch]);
      }
    }
  }
}

// ---------------- edge kernel, WAVE-LOCAL tiles (16 edges per wave), barrier-free
//                  main loop: [lazy e-update] + Ce GEMM (MFMA) + vectorized epilogue.
// MODE 0: layer 0. MODE 1: apply pending BN-e update, write e back. MODE 2: no write-back.
template <int MODE, int EZE, int EZN>
__global__ __launch_bounds__(256) void k_edge(void* __restrict__ e,
    void* __restrict__ e_new,
    const float* __restrict__ WC, const float* __restrict__ bC,
    const ushort* __restrict__ Dh, const ushort* __restrict__ Eh,
    const int* __restrict__ srcC, const int* __restrict__ dstC,
    float* __restrict__ stats) {
  __shared__ __align__(16) ushort Wt[DD * LDA];
  __shared__ __align__(16) ushort At[4][16 * LDA];   // per-wave tile
  __shared__ float sred[2 * DD];
  __shared__ float escl[DD], eshl[DD];
  const int tid = threadIdx.x;
  for (int i = tid; i < DD * DD; i += 256) {
    const int k = i / DD, n = i - (i / DD) * DD;
    Wt[n * LDA + k] = f2bf(WC[i]);
  }
  if (tid < 2 * DD) sred[tid] = 0.f;
  if (MODE >= 1 && tid < DD) { escl[tid] = stats[576 + tid]; eshl[tid] = stats[672 + tid]; }
  __syncthreads();   // the ONLY block-wide barrier before the end flush
  const int w = tid >> 6, lane = tid & 63;
  const int lrow = lane & 15, lgrp = lane >> 4;
  // epilogue channel-group phases: q(it) = (it*64+lane) % 24, period 3 over it
  const int qq0 = lane % 24;
  const int qq1 = (lane + 16) % 24;
  const int qq2 = (lane + 8) % 24;
  const float4 bc0 = *(const float4*)&bC[qq0 * 4];
  const float4 bc1 = *(const float4*)&bC[qq1 * 4];
  const float4 bc2 = *(const float4*)&bC[qq2 * 4];
  float sacc0[4] = {0,0,0,0}, sacc1[4] = {0,0,0,0}, sacc2[4] = {0,0,0,0};
  float qacc0[4] = {0,0,0,0}, qacc1[4] = {0,0,0,0}, qacc2[4] = {0,0,0,0};

  const int NTW = EE / 16;                 // 50000 wave-tiles
  const int gwave = blockIdx.x * 4 + w;
  const int nwave = gridDim.x * 4;
  for (int t = gwave; t < NTW; t += nwave) {
    const size_t base = (size_t)t * 16;
    // ---- stage (wave-local): 16 rows x 12 groups-of-8 = 192 / 64 lanes = 3 each
#pragma unroll
    for (int it = 0; it < 3; it++) {
      const int idx = it * 64 + lane;
      const int r = idx / 12, g8 = idx - (idx / 12) * 12;
      const size_t gi8 = (base + r) * 12 + g8;
      float a[8];
      EST<EZE>::ld8(e, gi8, a);
      if (MODE >= 1) {
        float d[8];
        EST<EZN>::ld8(e_new, gi8, d);
        const int c = g8 * 8;
#pragma unroll
        for (int j = 0; j < 8; j++)
          a[j] += fmaxf(fmaf(d[j], escl[c + j], eshl[c + j]), 0.f);
        if (MODE == 1) EST<EZE>::st8(e, gi8, a);
      }
      ushort8_t o;
#pragma unroll
      for (int j = 0; j < 8; j++) o[j] = f2bf(a[j]);
      *(ushort8_t*)&At[w][r * LDA + g8 * 8] = o;
    }
    // ---- MFMA: this wave's 16 rows x 96 channels (compiler inserts lgkmcnt waits)
    f32x4 acc[6];
#pragma unroll
    for (int nt = 0; nt < 6; nt++) { acc[nt][0]=0.f; acc[nt][1]=0.f; acc[nt][2]=0.f; acc[nt][3]=0.f; }
#pragma unroll
    for (int kk = 0; kk < 3; kk++) {
      const bf16x8 af = *(const bf16x8*)&At[w][lrow * LDA + kk * 32 + lgrp * 8];
#pragma unroll
      for (int nt = 0; nt < 6; nt++) {
        const bf16x8 bfr = *(const bf16x8*)&Wt[(nt * 16 + lrow) * LDA + kk * 32 + lgrp * 8];
        acc[nt] = __builtin_amdgcn_mfma_f32_16x16x32_bf16(af, bfr, acc[nt], 0, 0, 0);
      }
    }
    // ---- acc -> At (bf16), wave-local
#pragma unroll
    for (int j = 0; j < 4; j++) {
#pragma unroll
      for (int nt = 0; nt < 6; nt++) {
        At[w][(lgrp * 4 + j) * LDA + nt * 16 + lrow] = f2bf(acc[nt][j]);
      }
    }
    // ---- epilogue: row-major vectorized; 16 rows x 24 groups = 384 / 64 = 6 each
#pragma unroll
    for (int it = 0; it < 6; it++) {
      const int idx = it * 64 + lane;
      const int r16 = idx / 24, gq = idx - (idx / 24) * 24;
      const size_t pos = base + r16;
      const int s = srcC[pos], d2 = dstC[pos];
      const ushort4 av = *(const ushort4*)&At[w][r16 * LDA + gq * 4];
      const ushort4 dv = *(const ushort4*)&Dh[(size_t)s * DD + gq * 4];
      const ushort4 ev = *(const ushort4*)&Eh[(size_t)d2 * DD + gq * 4];
      const float4 bc = (it % 3 == 0) ? bc0 : (it % 3 == 1) ? bc1 : bc2;
      float4 v;
      v.x = bfu2f(av.x) + bc.x + bfu2f(dv.x) + bfu2f(ev.x);
      v.y = bfu2f(av.y) + bc.y + bfu2f(dv.y) + bfu2f(ev.y);
      v.z = bfu2f(av.z) + bc.z + bfu2f(dv.z) + bfu2f(ev.z);
      v.w = bfu2f(av.w) + bc.w + bfu2f(dv.w) + bfu2f(ev.w);
      if (it % 3 == 0) {
        sacc0[0]+=v.x; sacc0[1]+=v.y; sacc0[2]+=v.z; sacc0[3]+=v.w;
        qacc0[0]+=v.x*v.x; qacc0[1]+=v.y*v.y; qacc0[2]+=v.z*v.z; qacc0[3]+=v.w*v.w;
      } else if (it % 3 == 1) {
        sacc1[0]+=v.x; sacc1[1]+=v.y; sacc1[2]+=v.z; sacc1[3]+=v.w;
        qacc1[0]+=v.x*v.x; qacc1[1]+=v.y*v.y; qacc1[2]+=v.z*v.z; qacc1[3]+=v.w*v.w;
      } else {
        sacc2[0]+=v.x; sacc2[1]+=v.y; sacc2[2]+=v.z; sacc2[3]+=v.w;
        qacc2[0]+=v.x*v.x; qacc2[1]+=v.y*v.y; qacc2[2]+=v.z*v.z; qacc2[3]+=v.w*v.w;
      }
      EST<EZN>::st(e_new, pos * 24 + gq, v);
    }
  }
  // ---- flush BN-e partials
#pragma unroll
  for (int c = 0; c < 4; c++) {
    atomicAdd(&sred[qq0 * 4 + c], sacc0[c]);
    atomicAdd(&sred[DD + qq0 * 4 + c], qacc0[c]);
    atomicAdd(&sred[qq1 * 4 + c], sacc1[c]);
    atomicAdd(&sred[DD + qq1 * 4 + c], qacc1[c]);
    atomicAdd(&sred[qq2 * 4 + c], sacc2[c]);
    atomicAdd(&sred[DD + qq2 * 4 + c], qacc2[c]);
  }
  __syncthreads();
  if (tid < 2 * DD) atomicAdd(&stats[tid], sred[tid]);
}

// ---------------- CSR aggregation: num/den in registers, hn = Ah + num/(den+eps),
//                  BN-h stats. Half-wave per node; 2-way edge unroll for MLP.
template <int EZN>
__global__ __launch_bounds__(256) void k_agg(const void* __restrict__ e_new,
    const int* __restrict__ srcC, const int* __restrict__ rowptr,
    const ushort* __restrict__ Bh, ushort* __restrict__ hn,
    float* __restrict__ stats) {
  __shared__ float sred[2 * DD];
  if (threadIdx.x < 2 * DD) sred[threadIdx.x] = 0.f;
  __syncthreads();
  const int hw = threadIdx.x >> 5, lane = threadIdx.x & 31;
  const int c0 = lane, c1 = lane + 32, c2 = lane + 64;
  float sa0 = 0, sa1 = 0, sa2 = 0, qa0 = 0, qa1 = 0, qa2 = 0;
  for (int n = blockIdx.x * 8 + hw; n < NN; n += gridDim.x * 8) {
    const int rs = rowptr[n], re = rowptr[n + 1];
    float n0 = 0, n1 = 0, n2 = 0, d0 = 0, d1 = 0, d2 = 0;
    int p = rs;
    for (; p + 2 <= re; p += 2) {
      const int sA = srcC[p], sB = srcC[p + 1];
      const float vA0 = EST<EZN>::ld1c(e_new, (size_t)p, c0);
      const float vA1 = EST<EZN>::ld1c(e_new, (size_t)p, c1);
      const float vA2 = EST<EZN>::ld1c(e_new, (size_t)p, c2);
      const float vB0 = EST<EZN>::ld1c(e_new, (size_t)(p + 1), c0);
      const float vB1 = EST<EZN>::ld1c(e_new, (size_t)(p + 1), c1);
      const float vB2 = EST<EZN>::ld1c(e_new, (size_t)(p + 1), c2);
      const size_t sbA = (size_t)sA * DD, sbB = (size_t)sB * DD;
      const float bA0 = bfu2f(Bh[sbA + c0]), bA1 = bfu2f(Bh[sbA + c1]), bA2 = bfu2f(Bh[sbA + c2]);
      const float bB0 = bfu2f(Bh[sbB + c0]), bB1 = bfu2f(Bh[sbB + c1]), bB2 = bfu2f(Bh[sbB + c2]);
      const float gA0 = 1.f / (1.f + __expf(-vA0));
      const float gA1 = 1.f / (1.f + __expf(-vA1));
      const float gA2 = 1.f / (1.f + __expf(-vA2));
      const float gB0 = 1.f / (1.f + __expf(-vB0));
      const float gB1 = 1.f / (1.f + __expf(-vB1));
      const float gB2 = 1.f / (1.f + __expf(-vB2));
      n0 += gA0 * bA0 + gB0 * bB0; d0 += gA0 + gB0;
      n1 += gA1 * bA1 + gB1 * bB1; d1 += gA1 + gB1;
      n2 += gA2 * bA2 + gB2 * bB2; d2 += gA2 + gB2;
    }
    if (p < re) {
      const int s = srcC[p];
      const float v0 = EST<EZN>::ld1c(e_new, (size_t)p, c0);
      const float v1 = EST<EZN>::ld1c(e_new, (size_t)p, c1);
      const float v2 = EST<EZN>::ld1c(e_new, (size_t)p, c2);
      const float g0 = 1.f / (1.f + __expf(-v0));
      const float g1 = 1.f / (1.f + __expf(-v1));
      const float g2 = 1.f / (1.f + __expf(-v2));
      const size_t sb = (size_t)s * DD;
      n0 += g0 * bfu2f(Bh[sb + c0]); d0 += g0;
      n1 += g1 * bfu2f(Bh[sb + c1]); d1 += g1;
      n2 += g2 * bfu2f(Bh[sb + c2]); d2 += g2;
    }
    const size_t hb = (size_t)n * DD;
    const float v0 = bfu2f(hn[hb + c0]) + n0 / (d0 + 1e-6f);
    const float v1 = bfu2f(hn[hb + c1]) + n1 / (d1 + 1e-6f);
    const float v2 = bfu2f(hn[hb + c2]) + n2 / (d2 + 1e-6f);
    hn[hb + c0] = f2bf(v0); hn[hb + c1] = f2bf(v1); hn[hb + c2] = f2bf(v2);
    sa0 += v0; qa0 += v0 * v0;
    sa1 += v1; qa1 += v1 * v1;
    sa2 += v2; qa2 += v2 * v2;
  }
  atomicAdd(&sred[c0], sa0); atomicAdd(&sred[c1], sa1); atomicAdd(&sred[c2], sa2);
  atomicAdd(&sred[DD + c0], qa0); atomicAdd(&sred[DD + c1], qa1); atomicAdd(&sred[DD + c2], qa2);
  __syncthreads();
  if (threadIdx.x < 2 * DD) atomicAdd(&stats[192 + threadIdx.x], sred[threadIdx.x]);
}

// ---------------- finalize BN stats -> scale/shift; zero raw slots for next layer
__global__ void k_finalize(float* __restrict__ stats,
    const float* __restrict__ g_h, const float* __restrict__ b_h,
    const float* __restrict__ g_e, const float* __restrict__ b_e) {
  const int c = threadIdx.x;
  if (c < DD) {
    const float mu_h = stats[192 + c] / (float)NN;
    const float var_h = stats[288 + c] / (float)NN - mu_h * mu_h;
    const float sc_h = g_h[c] * rsqrtf(var_h + 1e-5f);
    const float mu_e = stats[c] / (float)EE;
    const float var_e = stats[96 + c] / (float)EE - mu_e * mu_e;
    const float sc_e = g_e[c] * rsqrtf(var_e + 1e-5f);
    stats[384 + c] = sc_h;
    stats[480 + c] = b_h[c] - mu_h * sc_h;
    stats[576 + c] = sc_e;
    stats[672 + c] = b_e[c] - mu_e * sc_e;
    stats[c] = 0.f; stats[96 + c] = 0.f; stats[192 + c] = 0.f; stats[288 + c] = 0.f;
  }
}

__global__ __launch_bounds__(256) void k_update_h(ushort* __restrict__ h,
    const ushort* __restrict__ hn, const float* __restrict__ stats) {
  int idx = blockIdx.x * 256 + threadIdx.x;
  const int stride = gridDim.x * 256;
  for (; idx < NN * DD; idx += stride) {
    const int c = idx % DD;
    const float v = fmaf(bfu2f(hn[idx]), stats[384 + c], stats[480 + c]);
    h[idx] = f2bf(bfu2f(h[idx]) + fmaxf(v, 0.f));
  }
}

// ------------------------------------------------------------------- MLP head
__global__ __launch_bounds__(256) void k_head(const ushort* __restrict__ h,
    const float* __restrict__ W1, const float* __restrict__ b1,
    const float* __restrict__ W2, const float* __restrict__ b2,
    const float* __restrict__ ma, float* __restrict__ out) {
  __shared__ float W1l[DD * NHID];
  __shared__ float W2l[NHID * NOUT];
  __shared__ float hid[4][NHID];
  __shared__ float hrow[4][DD];
  for (int i = threadIdx.x; i < DD * NHID; i += 256) W1l[i] = W1[i];
  for (int i = threadIdx.x; i < NHID * NOUT; i += 256) W2l[i] = W2[i];
  __syncthreads();
  const int w = threadIdx.x >> 6, lane = threadIdx.x & 63;
  for (int n = blockIdx.x * 4 + w; n < NN; n += gridDim.x * 4) {
    const ushort* hp = h + (size_t)n * DD;
    if (lane < DD - 64) hrow[w][64 + lane] = bfu2f(hp[64 + lane]);
    hrow[w][lane] = bfu2f(hp[lane]);
    float a0 = b1[lane], a1 = b1[64 + lane];
    for (int k = 0; k < DD; k++) {
      const float x = hrow[w][k];
      a0 = fmaf(x, W1l[k * NHID + lane], a0);
      a1 = fmaf(x, W1l[k * NHID + 64 + lane], a1);
    }
    hid[w][lane] = fmaxf(a0, 0.f);
    hid[w][64 + lane] = fmaxf(a1, 0.f);
    if (lane < NOUT) {
      float o = b2[lane];
      for (int k = 0; k < NHID; k++) o = fmaf(hid[w][k], W2l[k * NOUT + lane], o);
      out[(size_t)n * NOUT + lane] = ma[n] * tanhf(o);
    }
  }
}

// ----------------------------------------------------------------------------
extern "C" void kernel_launch(void* const* d_in, const int* in_sizes, int n_in,
                              void* d_out, int out_size, void* d_ws, size_t ws_size,
                              hipStream_t stream) {
  const float* h1  = (const float*)d_in[0];
  const float* h2  = (const float*)d_in[1];
  const float* z   = (const float*)d_in[2];
  const float* ef  = (const float*)d_in[3];
  const float* ma  = (const float*)d_in[4];
  const float* Wh  = (const float*)d_in[5];
  const float* bh  = (const float*)d_in[6];
  const float* We  = (const float*)d_in[7];
  const float* be  = (const float*)d_in[8];
  const float* WA  = (const float*)d_in[9];
  const float* bA  = (const float*)d_in[10];
  const float* WB  = (const float*)d_in[11];
  const float* bB  = (const float*)d_in[12];
  const float* WC  = (const float*)d_in[13];
  const float* bC  = (const float*)d_in[14];
  const float* WD  = (const float*)d_in[15];
  const float* bD  = (const float*)d_in[16];
  const float* WE  = (const float*)d_in[17];
  const float* bE  = (const float*)d_in[18];
  const float* bn_h_g = (const float*)d_in[19];
  const float* bn_h_b = (const float*)d_in[20];
  const float* bn_e_g = (const float*)d_in[21];
  const float* bn_e_b = (const float*)d_in[22];
  const float* W1  = (const float*)d_in[23];
  const float* b1  = (const float*)d_in[24];
  const float* W2  = (const float*)d_in[25];
  const float* b2  = (const float*)d_in[26];
  const int*   src = (const int*)d_in[27];
  const int*   dst = (const int*)d_in[28];

  const size_t E_ELEMS = (size_t)EE * DD;
  const size_t N_ELEMS = (size_t)NN * DD;
  int tier;
  if (ws_size >= 455000000UL)      tier = 0;   // e bf16 + e_new bf16
  else if (ws_size >= 297000000UL) tier = 1;   // e fp8  + e_new bf16  (confirmed r5/r6)
  else                             tier = 2;   // e fp8  + e_new fp8
  const size_t esze = (tier == 0) ? 2 : 1;
  const size_t eszn = (tier <= 1) ? 2 : 1;

  char* p = (char*)d_ws;
  void* e     = (void*)p; p += E_ELEMS * esze;
  void* e_new = (void*)p; p += E_ELEMS * eszn;
  ushort* h   = (ushort*)p; p += N_ELEMS * 2;
  ushort* hn  = (ushort*)p; p += N_ELEMS * 2;
  ushort* Bhb = (ushort*)p; p += N_ELEMS * 2;
  ushort* Dhb = (ushort*)p; p += N_ELEMS * 2;
  ushort* Ehb = (ushort*)p; p += N_ELEMS * 2;
  int* cnt    = (int*)p; p += (size_t)NN * 4;
  int* rowptr = (int*)p; p += (size_t)(NN + 1) * 4;
  int* cursor = (int*)p; p += (size_t)NN * 4;
  int* perm   = (int*)p; p += (size_t)EE * 4;
  int* srcC   = (int*)p; p += (size_t)EE * 4;
  int* dstC   = (int*)p; p += (size_t)EE * 4;
  float* stats = (float*)p;

  k_zero_init<<<64, 256, 0, stream>>>(cnt, stats);
  k_hist<<<3125, 256, 0, stream>>>(dst, cnt);
  k_scan<<<1, 256, 0, stream>>>(cnt, rowptr, cursor);
  k_scatter<<<3125, 256, 0, stream>>>(src, dst, cursor, perm, srcC, dstC);
  k_embed_h<<<1024, 256, 0, stream>>>(h1, h2, z, Wh, bh, h);
  if (esze == 2) k_embed_e<2><<<2048, 256, 0, stream>>>(ef, We, be, perm, e);
  else           k_embed_e<1><<<2048, 256, 0, stream>>>(ef, We, be, perm, e);

  for (int l = 0; l < 4; l++) {
    dim3 gn(782, 4);
    k_ngemm<<<gn, 256, 0, stream>>>(h,
        WA + l * DD * DD, WB + l * DD * DD, WD + l * DD * DD, WE + l * DD * DD,
        bA + l * DD, bB + l * DD, bD + l * DD, bE + l * DD,
        hn, Bhb, Dhb, Ehb);
    const float* WCl = WC + l * DD * DD;
    const float* bCl = bC + l * DD;
#define EDGE_ARGS e, e_new, WCl, bCl, Dhb, Ehb, srcC, dstC, stats
    if (tier == 0) {
      if (l == 0)      k_edge<0,2,2><<<2500, 256, 0, stream>>>(EDGE_ARGS);
      else if (l < 3)  k_edge<1,2,2><<<2500, 256, 0, stream>>>(EDGE_ARGS);
      else             k_edge<2,2,2><<<2500, 256, 0, stream>>>(EDGE_ARGS);
    } else if (tier == 1) {
      if (l == 0)      k_edge<0,1,2><<<2500, 256, 0, stream>>>(EDGE_ARGS);
      else if (l < 3)  k_edge<1,1,2><<<2500, 256, 0, stream>>>(EDGE_ARGS);
      else             k_edge<2,1,2><<<2500, 256, 0, stream>>>(EDGE_ARGS);
    } else {
      if (l == 0)      k_edge<0,1,1><<<2500, 256, 0, stream>>>(EDGE_ARGS);
      else if (l < 3)  k_edge<1,1,1><<<2500, 256, 0, stream>>>(EDGE_ARGS);
      else             k_edge<2,1,1><<<2500, 256, 0, stream>>>(EDGE_ARGS);
    }
#undef EDGE_ARGS
    if (eszn == 2) k_agg<2><<<1024, 256, 0, stream>>>(e_new, srcC, rowptr, Bhb, hn, stats);
    else           k_agg<1><<<1024, 256, 0, stream>>>(e_new, srcC, rowptr, Bhb, hn, stats);
    k_finalize<<<1, 128, 0, stream>>>(stats,
        bn_h_g + l * DD, bn_h_b + l * DD, bn_e_g + l * DD, bn_e_b + l * DD);
    k_update_h<<<1024, 256, 0, stream>>>(h, hn, stats);
  }

  k_head<<<1024, 256, 0, stream>>>(h, W1, b1, W2, b2, ma, (float*)d_out);
}

// Round 8
// 1962.504 us; speedup vs baseline: 1.5028x; 1.5028x over previous
//
#include <hip/hip_runtime.h>
#include <math.h>

#define NN 50000
#define EE 800000
#define DD 96
#define NHID 128
#define NOUT 8
#define LDA 104   // padded LDS row stride in bf16 elems (208 B; 16B-aligned)

typedef unsigned int uint32;
typedef float floatx2 __attribute__((ext_vector_type(2)));
typedef float f32x4 __attribute__((ext_vector_type(4)));
typedef short bf16x8 __attribute__((ext_vector_type(8)));

__device__ __forceinline__ float bfu2f(ushort u) {
  union { uint32 u; float f; } v; v.u = ((uint32)u) << 16; return v.f;
}
__device__ __forceinline__ ushort f2bf(float x) {
  union { float f; uint32 u; } v; v.f = x;
  uint32 r = (v.u + 0x7fffu + ((v.u >> 16) & 1u)) >> 16;
  return (ushort)r;
}

// Edge storage traits: 2 -> bf16, 1 -> fp8 e4m3 (OCP, HW cvt). Index: group of 4 channels.
template <int ESZ> struct EST;
template <> struct EST<2> {
  static __device__ __forceinline__ float4 ld(const void* e, size_t grp) {
    const ushort4 a = ((const ushort4*)e)[grp];
    return make_float4(bfu2f(a.x), bfu2f(a.y), bfu2f(a.z), bfu2f(a.w));
  }
  static __device__ __forceinline__ void st(void* e, size_t grp, float4 v) {
    ushort4 o; o.x = f2bf(v.x); o.y = f2bf(v.y); o.z = f2bf(v.z); o.w = f2bf(v.w);
    ((ushort4*)e)[grp] = o;
  }
  static __device__ __forceinline__ float ld1c(const void* e, size_t pos, int c) {
    return bfu2f(((const ushort*)e)[pos * DD + c]);
  }
};
template <> struct EST<1> {
  static __device__ __forceinline__ float4 ld(const void* e, size_t grp) {
    const int u = ((const int*)e)[grp];
    floatx2 lo = __builtin_amdgcn_cvt_pk_f32_fp8(u, false);
    floatx2 hi = __builtin_amdgcn_cvt_pk_f32_fp8(u, true);
    return make_float4(lo[0], lo[1], hi[0], hi[1]);
  }
  static __device__ __forceinline__ void st(void* e, size_t grp, float4 v) {
    int u = 0;
    u = __builtin_amdgcn_cvt_pk_fp8_f32(v.x, v.y, u, false);
    u = __builtin_amdgcn_cvt_pk_fp8_f32(v.z, v.w, u, true);
    ((int*)e)[grp] = u;
  }
  static __device__ __forceinline__ float ld1c(const void* e, size_t pos, int c) {
    const int dw = ((const int*)e)[pos * (DD / 4) + (c >> 2)];
    floatx2 lo = __builtin_amdgcn_cvt_pk_f32_fp8(dw, false);
    floatx2 hi = __builtin_amdgcn_cvt_pk_f32_fp8(dw, true);
    return (c & 2) ? ((c & 1) ? hi[1] : hi[0]) : ((c & 1) ? lo[1] : lo[0]);
  }
};

// ------------------------------------------------------------- init / CSR build
__global__ __launch_bounds__(256) void k_zero_init(int* __restrict__ cnt,
    float* __restrict__ stats) {
  int i = blockIdx.x * 256 + threadIdx.x;
  const int str = gridDim.x * 256;
  for (; i < NN; i += str) cnt[i] = 0;
  if (blockIdx.x == 0)
    for (int j = threadIdx.x; j < 768; j += 256) stats[j] = 0.f;
}

__global__ __launch_bounds__(256) void k_hist(const int* __restrict__ dst,
    int* __restrict__ cnt) {
  const int i = blockIdx.x * 256 + threadIdx.x;
  if (i < EE) atomicAdd(&cnt[dst[i]], 1);
}

__global__ __launch_bounds__(256) void k_scan(const int* __restrict__ cnt,
    int* __restrict__ rowptr, int* __restrict__ cursor) {
  __shared__ int part[256];
  const int t = threadIdx.x;
  const int CH = (NN + 255) / 256;
  const int lo = t * CH, hi = min((t + 1) * CH, NN);
  int s = 0;
  for (int i = lo; i < hi; i++) s += cnt[i];
  part[t] = s;
  __syncthreads();
  for (int off = 1; off < 256; off <<= 1) {
    int v = (t >= off) ? part[t - off] : 0;
    __syncthreads();
    part[t] += v;
    __syncthreads();
  }
  int base = (t == 0) ? 0 : part[t - 1];
  for (int i = lo; i < hi; i++) {
    rowptr[i] = base; cursor[i] = base; base += cnt[i];
  }
  if (t == 255) rowptr[NN] = base;
}

__global__ __launch_bounds__(256) void k_scatter(const int* __restrict__ src,
    const int* __restrict__ dst, int* __restrict__ cursor,
    int* __restrict__ perm, int* __restrict__ srcC, int* __restrict__ dstC) {
  const int i = blockIdx.x * 256 + threadIdx.x;
  if (i < EE) {
    const int d = dst[i];
    const int pos = atomicAdd(&cursor[d], 1);
    perm[pos] = i; srcC[pos] = src[i]; dstC[pos] = d;
  }
}

// ---------------------------------------------------------------- embeddings
__global__ __launch_bounds__(256) void k_embed_h(const float* __restrict__ h1,
    const float* __restrict__ h2, const float* __restrict__ z,
    const float* __restrict__ W, const float* __restrict__ b,
    ushort* __restrict__ h) {
  int idx = blockIdx.x * 256 + threadIdx.x;
  const int total = NN * DD;
  const int stride = gridDim.x * 256;
  for (; idx < total; idx += stride) {
    int n = idx / DD, c = idx - n * DD;
    float acc = b[c];
#pragma unroll
    for (int k = 0; k < 6; k++)  acc = fmaf(h1[n * 6 + k], W[k * DD + c], acc);
#pragma unroll
    for (int k = 0; k < 4; k++)  acc = fmaf(h2[n * 4 + k], W[(6 + k) * DD + c], acc);
#pragma unroll
    for (int k = 0; k < 16; k++) acc = fmaf(z[n * 16 + k], W[(10 + k) * DD + c], acc);
    h[idx] = f2bf(acc);
  }
}

template <int EZ>
__global__ __launch_bounds__(256) void k_embed_e(const float* __restrict__ ef,
    const float* __restrict__ W, const float* __restrict__ b,
    const int* __restrict__ perm, void* __restrict__ e) {
  int g = blockIdx.x * 256 + threadIdx.x;
  const int totalg = EE * (DD / 4);
  const int stride = gridDim.x * 256;
  for (; g < totalg; g += stride) {
    const int pos = g / 24, cg = (g - pos * 24) * 4;
    const int orig = perm[pos];
    const float f0 = ef[orig * 4], f1 = ef[orig * 4 + 1];
    const float f2 = ef[orig * 4 + 2], f3 = ef[orig * 4 + 3];
    float4 acc;
    acc.x = b[cg+0] + f0*W[cg+0] + f1*W[DD+cg+0] + f2*W[2*DD+cg+0] + f3*W[3*DD+cg+0];
    acc.y = b[cg+1] + f0*W[cg+1] + f1*W[DD+cg+1] + f2*W[2*DD+cg+1] + f3*W[3*DD+cg+1];
    acc.z = b[cg+2] + f0*W[cg+2] + f1*W[DD+cg+2] + f2*W[2*DD+cg+2] + f3*W[3*DD+cg+2];
    acc.w = b[cg+3] + f0*W[cg+3] + f1*W[DD+cg+3] + f2*W[2*DD+cg+3] + f3*W[3*DD+cg+3];
    EST<EZ>::st(e, g, acc);
  }
}

// ---------------- node GEMMs via MFMA: one block = 128 rows x all 4 matrices,
//                  with fused lazy h-update (h += relu(BN(hn)) from prev layer).
template <int LAZY>
__global__ __launch_bounds__(256) void k_ngemm(ushort* __restrict__ h,
    const float* __restrict__ WAp, const float* __restrict__ WBp,
    const float* __restrict__ WDp, const float* __restrict__ WEp,
    const float* __restrict__ bAp, const float* __restrict__ bBp,
    const float* __restrict__ bDp, const float* __restrict__ bEp,
    ushort* __restrict__ oA, ushort* __restrict__ oB,
    ushort* __restrict__ oD, ushort* __restrict__ oE,
    const float* __restrict__ stats) {
  __shared__ __align__(16) ushort Wt[DD * LDA];       // 20.0 KB
  __shared__ __align__(16) ushort At[128 * LDA];      // 26.6 KB
  __shared__ float uscl[DD], ushf[DD];
  const int tid = threadIdx.x;
  if (LAZY && tid < DD) { uscl[tid] = stats[384 + tid]; ushf[tid] = stats[480 + tid]; }
  if (LAZY) __syncthreads();
  const int base = blockIdx.x * 128;
  // stage At (+ lazy update, write h back)
#pragma unroll
  for (int ii = 0; ii < 12; ii++) {
    const int i = ii * 256 + tid;
    const int r = i / 24, q = i - (i / 24) * 24;
    const int row = base + r;
    ushort4 a; a.x = 0; a.y = 0; a.z = 0; a.w = 0;
    if (row < NN) {
      a = ((const ushort4*)h)[(size_t)row * 24 + q];
      if (LAZY) {
        const ushort4 u = ((const ushort4*)0)[0], *dummy = &u; (void)dummy;
      }
    }
    if (LAZY && row < NN) {
      const ushort4 u = ((const ushort4*)oA)[(size_t)row * 24 + q];  // oA == hn (prev h_new)
      const int c = q * 4;
      float f0 = bfu2f(a.x) + fmaxf(fmaf(bfu2f(u.x), uscl[c],     ushf[c]),     0.f);
      float f1 = bfu2f(a.y) + fmaxf(fmaf(bfu2f(u.y), uscl[c + 1], ushf[c + 1]), 0.f);
      float f2 = bfu2f(a.z) + fmaxf(fmaf(bfu2f(u.z), uscl[c + 2], ushf[c + 2]), 0.f);
      float f3 = bfu2f(a.w) + fmaxf(fmaf(bfu2f(u.w), uscl[c + 3], ushf[c + 3]), 0.f);
      a.x = f2bf(f0); a.y = f2bf(f1); a.z = f2bf(f2); a.w = f2bf(f3);
      ((ushort4*)h)[(size_t)row * 24 + q] = a;
    }
    *(ushort4*)&At[r * LDA + q * 4] = a;
  }
  const int w = tid >> 6, lane = tid & 63;
  const int lrow = lane & 15, lgrp = lane >> 4;
#pragma unroll
  for (int m = 0; m < 4; m++) {
    const float* W  = (m == 0) ? WAp : (m == 1) ? WBp : (m == 2) ? WDp : WEp;
    const float* bi = (m == 0) ? bAp : (m == 1) ? bBp : (m == 2) ? bDp : bEp;
    ushort* out     = (m == 0) ? oA  : (m == 1) ? oB  : (m == 2) ? oD  : oE;
    // stage Wt (bf16 transposed [n][k])
#pragma unroll
    for (int ii = 0; ii < 36; ii++) {
      const int i = ii * 256 + tid;
      const int k = i / DD, n = i - (i / DD) * DD;
      Wt[n * LDA + k] = f2bf(W[i]);
    }
    __syncthreads();
    f32x4 acc[2][6];
#pragma unroll
    for (int rt2 = 0; rt2 < 2; rt2++)
#pragma unroll
      for (int nt = 0; nt < 6; nt++) {
        acc[rt2][nt][0] = 0.f; acc[rt2][nt][1] = 0.f;
        acc[rt2][nt][2] = 0.f; acc[rt2][nt][3] = 0.f;
      }
#pragma unroll
    for (int rt2 = 0; rt2 < 2; rt2++) {
      const int rt = w * 2 + rt2;
#pragma unroll
      for (int kk = 0; kk < 3; kk++) {
        const bf16x8 af = *(const bf16x8*)&At[(rt * 16 + lrow) * LDA + kk * 32 + lgrp * 8];
#pragma unroll
        for (int nt = 0; nt < 6; nt++) {
          const bf16x8 bfr = *(const bf16x8*)&Wt[(nt * 16 + lrow) * LDA + kk * 32 + lgrp * 8];
          acc[rt2][nt] = __builtin_amdgcn_mfma_f32_16x16x32_bf16(af, bfr, acc[rt2][nt], 0, 0, 0);
        }
      }
    }
#pragma unroll
    for (int rt2 = 0; rt2 < 2; rt2++) {
      const int rt = w * 2 + rt2;
#pragma unroll
      for (int j = 0; j < 4; j++) {
        const int row = base + rt * 16 + lgrp * 4 + j;
        if (row < NN) {
#pragma unroll
          for (int nt = 0; nt < 6; nt++) {
            const int ch = nt * 16 + lrow;
            out[(size_t)row * DD + ch] = f2bf(acc[rt2][nt][j] + bi[ch]);
          }
        }
      }
    }
    __syncthreads();
  }
}

// ---------------- edge kernel (r6-proven): [lazy e-update] + Ce GEMM (MFMA) +
//                  vectorized epilogue (Dh[src]+Eh[dst] + e_new store + BN-e stats).
// MODE 0: layer 0. MODE 1: apply pending BN-e update, write e back. MODE 2: no write-back.
template <int MODE, int EZE, int EZN>
__global__ __launch_bounds__(256) void k_edge(void* __restrict__ e,
    void* __restrict__ e_new,
    const float* __restrict__ WC, const float* __restrict__ bC,
    const ushort* __restrict__ Dh, const ushort* __restrict__ Eh,
    const int* __restrict__ srcC, const int* __restrict__ dstC,
    float* __restrict__ stats) {
  __shared__ __align__(16) ushort Wt[DD * LDA];
  __shared__ __align__(16) ushort At[64 * LDA];
  __shared__ float sred[2 * DD];
  __shared__ float escl[DD], eshl[DD];
  __shared__ int sidx_s[64], sidx_d[64];
  const int tid = threadIdx.x;
  for (int i = tid; i < DD * DD; i += 256) {
    const int k = i / DD, n = i - (i / DD) * DD;
    Wt[n * LDA + k] = f2bf(WC[i]);
  }
  if (tid < 2 * DD) sred[tid] = 0.f;
  if (MODE >= 1 && tid < DD) { escl[tid] = stats[576 + tid]; eshl[tid] = stats[672 + tid]; }
  __syncthreads();
  const int w = tid >> 6, lane = tid & 63;
  const int lrow = lane & 15, lgrp = lane >> 4;
  const int qq0 = lane % 24;
  const int qq1 = (lane + 16) % 24;
  const int qq2 = (lane + 8) % 24;
  const float4 bc0 = *(const float4*)&bC[qq0 * 4];
  const float4 bc1 = *(const float4*)&bC[qq1 * 4];
  const float4 bc2 = *(const float4*)&bC[qq2 * 4];
  float sacc0[4] = {0,0,0,0}, sacc1[4] = {0,0,0,0}, sacc2[4] = {0,0,0,0};
  float qacc0[4] = {0,0,0,0}, qacc1[4] = {0,0,0,0}, qacc2[4] = {0,0,0,0};

  const int NT = EE / 64;   // 12500
  for (int t = blockIdx.x; t < NT; t += gridDim.x) {
    const size_t base = (size_t)t * 64;
#pragma unroll
    for (int ii = 0; ii < 6; ii++) {
      const int i = ii * 256 + tid;
      const int r = i / 24, gq = i - (i / 24) * 24;
      const size_t gi = (base + r) * 24 + gq;
      float4 a = EST<EZE>::ld(e, gi);
      if (MODE >= 1) {
        const float4 d = EST<EZN>::ld(e_new, gi);
        const int c = gq * 4;
        a.x += fmaxf(fmaf(d.x, escl[c],     eshl[c]),     0.f);
        a.y += fmaxf(fmaf(d.y, escl[c + 1], eshl[c + 1]), 0.f);
        a.z += fmaxf(fmaf(d.z, escl[c + 2], eshl[c + 2]), 0.f);
        a.w += fmaxf(fmaf(d.w, escl[c + 3], eshl[c + 3]), 0.f);
        if (MODE == 1) EST<EZE>::st(e, gi, a);
      }
      ushort4 o; o.x = f2bf(a.x); o.y = f2bf(a.y); o.z = f2bf(a.z); o.w = f2bf(a.w);
      *(ushort4*)&At[r * LDA + gq * 4] = o;
    }
    if (tid < 64) { sidx_s[tid] = srcC[base + tid]; sidx_d[tid] = dstC[base + tid]; }
    __syncthreads();
    f32x4 acc[6];
#pragma unroll
    for (int nt = 0; nt < 6; nt++) { acc[nt][0]=0.f; acc[nt][1]=0.f; acc[nt][2]=0.f; acc[nt][3]=0.f; }
#pragma unroll
    for (int kk = 0; kk < 3; kk++) {
      const bf16x8 af = *(const bf16x8*)&At[(w * 16 + lrow) * LDA + kk * 32 + lgrp * 8];
#pragma unroll
      for (int nt = 0; nt < 6; nt++) {
        const bf16x8 bfr = *(const bf16x8*)&Wt[(nt * 16 + lrow) * LDA + kk * 32 + lgrp * 8];
        acc[nt] = __builtin_amdgcn_mfma_f32_16x16x32_bf16(af, bfr, acc[nt], 0, 0, 0);
      }
    }
#pragma unroll
    for (int j = 0; j < 4; j++) {
#pragma unroll
      for (int nt = 0; nt < 6; nt++) {
        At[(w * 16 + lgrp * 4 + j) * LDA + nt * 16 + lrow] = f2bf(acc[nt][j]);
      }
    }
#pragma unroll
    for (int it = 0; it < 6; it++) {
      const int idx = it * 64 + lane;
      const int r16 = idx / 24, gq = idx - (idx / 24) * 24;
      const int row = w * 16 + r16;
      const size_t pos = base + row;
      const int s = sidx_s[row], d2 = sidx_d[row];
      const ushort4 av = *(const ushort4*)&At[row * LDA + gq * 4];
      const ushort4 dv = *(const ushort4*)&Dh[(size_t)s * DD + gq * 4];
      const ushort4 ev = *(const ushort4*)&Eh[(size_t)d2 * DD + gq * 4];
      const float4 bc = (it % 3 == 0) ? bc0 : (it % 3 == 1) ? bc1 : bc2;
      float4 v;
      v.x = bfu2f(av.x) + bc.x + bfu2f(dv.x) + bfu2f(ev.x);
      v.y = bfu2f(av.y) + bc.y + bfu2f(dv.y) + bfu2f(ev.y);
      v.z = bfu2f(av.z) + bc.z + bfu2f(dv.z) + bfu2f(ev.z);
      v.w = bfu2f(av.w) + bc.w + bfu2f(dv.w) + bfu2f(ev.w);
      if (it % 3 == 0) {
        sacc0[0]+=v.x; sacc0[1]+=v.y; sacc0[2]+=v.z; sacc0[3]+=v.w;
        qacc0[0]+=v.x*v.x; qacc0[1]+=v.y*v.y; qacc0[2]+=v.z*v.z; qacc0[3]+=v.w*v.w;
      } else if (it % 3 == 1) {
        sacc1[0]+=v.x; sacc1[1]+=v.y; sacc1[2]+=v.z; sacc1[3]+=v.w;
        qacc1[0]+=v.x*v.x; qacc1[1]+=v.y*v.y; qacc1[2]+=v.z*v.z; qacc1[3]+=v.w*v.w;
      } else {
        sacc2[0]+=v.x; sacc2[1]+=v.y; sacc2[2]+=v.z; sacc2[3]+=v.w;
        qacc2[0]+=v.x*v.x; qacc2[1]+=v.y*v.y; qacc2[2]+=v.z*v.z; qacc2[3]+=v.w*v.w;
      }
      EST<EZN>::st(e_new, pos * 24 + gq, v);
    }
    __syncthreads();
  }
#pragma unroll
  for (int c = 0; c < 4; c++) {
    atomicAdd(&sred[qq0 * 4 + c], sacc0[c]);
    atomicAdd(&sred[DD + qq0 * 4 + c], qacc0[c]);
    atomicAdd(&sred[qq1 * 4 + c], sacc1[c]);
    atomicAdd(&sred[DD + qq1 * 4 + c], qacc1[c]);
    atomicAdd(&sred[qq2 * 4 + c], sacc2[c]);
    atomicAdd(&sred[DD + qq2 * 4 + c], qacc2[c]);
  }
  __syncthreads();
  if (tid < 2 * DD) atomicAdd(&stats[tid], sred[tid]);
}

// ---------------- CSR aggregation: num/den in registers, hn = Ah + num/(den+eps),
//                  BN-h stats. Half-wave per node; 2-way edge unroll.
template <int EZN>
__global__ __launch_bounds__(256) void k_agg(const void* __restrict__ e_new,
    const int* __restrict__ srcC, const int* __restrict__ rowptr,
    const ushort* __restrict__ Bh, ushort* __restrict__ hn,
    float* __restrict__ stats) {
  __shared__ float sred[2 * DD];
  if (threadIdx.x < 2 * DD) sred[threadIdx.x] = 0.f;
  __syncthreads();
  const int hw = threadIdx.x >> 5, lane = threadIdx.x & 31;
  const int c0 = lane, c1 = lane + 32, c2 = lane + 64;
  float sa0 = 0, sa1 = 0, sa2 = 0, qa0 = 0, qa1 = 0, qa2 = 0;
  for (int n = blockIdx.x * 8 + hw; n < NN; n += gridDim.x * 8) {
    const int rs = rowptr[n], re = rowptr[n + 1];
    float n0 = 0, n1 = 0, n2 = 0, d0 = 0, d1 = 0, d2 = 0;
    int p = rs;
    for (; p + 2 <= re; p += 2) {
      const int sA = srcC[p], sB = srcC[p + 1];
      const float vA0 = EST<EZN>::ld1c(e_new, (size_t)p, c0);
      const float vA1 = EST<EZN>::ld1c(e_new, (size_t)p, c1);
      const float vA2 = EST<EZN>::ld1c(e_new, (size_t)p, c2);
      const float vB0 = EST<EZN>::ld1c(e_new, (size_t)(p + 1), c0);
      const float vB1 = EST<EZN>::ld1c(e_new, (size_t)(p + 1), c1);
      const float vB2 = EST<EZN>::ld1c(e_new, (size_t)(p + 1), c2);
      const size_t sbA = (size_t)sA * DD, sbB = (size_t)sB * DD;
      const float bA0 = bfu2f(Bh[sbA + c0]), bA1 = bfu2f(Bh[sbA + c1]), bA2 = bfu2f(Bh[sbA + c2]);
      const float bB0 = bfu2f(Bh[sbB + c0]), bB1 = bfu2f(Bh[sbB + c1]), bB2 = bfu2f(Bh[sbB + c2]);
      const float gA0 = 1.f / (1.f + __expf(-vA0));
      const float gA1 = 1.f / (1.f + __expf(-vA1));
      const float gA2 = 1.f / (1.f + __expf(-vA2));
      const float gB0 = 1.f / (1.f + __expf(-vB0));
      const float gB1 = 1.f / (1.f + __expf(-vB1));
      const float gB2 = 1.f / (1.f + __expf(-vB2));
      n0 += gA0 * bA0 + gB0 * bB0; d0 += gA0 + gB0;
      n1 += gA1 * bA1 + gB1 * bB1; d1 += gA1 + gB1;
      n2 += gA2 * bA2 + gB2 * bB2; d2 += gA2 + gB2;
    }
    if (p < re) {
      const int s = srcC[p];
      const float v0 = EST<EZN>::ld1c(e_new, (size_t)p, c0);
      const float v1 = EST<EZN>::ld1c(e_new, (size_t)p, c1);
      const float v2 = EST<EZN>::ld1c(e_new, (size_t)p, c2);
      const float g0 = 1.f / (1.f + __expf(-v0));
      const float g1 = 1.f / (1.f + __expf(-v1));
      const float g2 = 1.f / (1.f + __expf(-v2));
      const size_t sb = (size_t)s * DD;
      n0 += g0 * bfu2f(Bh[sb + c0]); d0 += g0;
      n1 += g1 * bfu2f(Bh[sb + c1]); d1 += g1;
      n2 += g2 * bfu2f(Bh[sb + c2]); d2 += g2;
    }
    const size_t hb = (size_t)n * DD;
    const float v0 = bfu2f(hn[hb + c0]) + n0 / (d0 + 1e-6f);
    const float v1 = bfu2f(hn[hb + c1]) + n1 / (d1 + 1e-6f);
    const float v2 = bfu2f(hn[hb + c2]) + n2 / (d2 + 1e-6f);
    hn[hb + c0] = f2bf(v0); hn[hb + c1] = f2bf(v1); hn[hb + c2] = f2bf(v2);
    sa0 += v0; qa0 += v0 * v0;
    sa1 += v1; qa1 += v1 * v1;
    sa2 += v2; qa2 += v2 * v2;
  }
  atomicAdd(&sred[c0], sa0); atomicAdd(&sred[c1], sa1); atomicAdd(&sred[c2], sa2);
  atomicAdd(&sred[DD + c0], qa0); atomicAdd(&sred[DD + c1], qa1); atomicAdd(&sred[DD + c2], qa2);
  __syncthreads();
  if (threadIdx.x < 2 * DD) atomicAdd(&stats[192 + threadIdx.x], sred[threadIdx.x]);
}

// ---------------- finalize BN stats -> scale/shift; zero raw slots for next layer
__global__ void k_finalize(float* __restrict__ stats,
    const float* __restrict__ g_h, const float* __restrict__ b_h,
    const float* __restrict__ g_e, const float* __restrict__ b_e) {
  const int c = threadIdx.x;
  if (c < DD) {
    const float mu_h = stats[192 + c] / (float)NN;
    const float var_h = stats[288 + c] / (float)NN - mu_h * mu_h;
    const float sc_h = g_h[c] * rsqrtf(var_h + 1e-5f);
    const float mu_e = stats[c] / (float)EE;
    const float var_e = stats[96 + c] / (float)EE - mu_e * mu_e;
    const float sc_e = g_e[c] * rsqrtf(var_e + 1e-5f);
    stats[384 + c] = sc_h;
    stats[480 + c] = b_h[c] - mu_h * sc_h;
    stats[576 + c] = sc_e;
    stats[672 + c] = b_e[c] - mu_e * sc_e;
    stats[c] = 0.f; stats[96 + c] = 0.f; stats[192 + c] = 0.f; stats[288 + c] = 0.f;
  }
}

// ------------------------- MLP head with fused final h-update (layer-3 BN-h)
__global__ __launch_bounds__(256) void k_head(const ushort* __restrict__ h,
    const ushort* __restrict__ hn, const float* __restrict__ stats,
    const float* __restrict__ W1, const float* __restrict__ b1,
    const float* __restrict__ W2, const float* __restrict__ b2,
    const float* __restrict__ ma, float* __restrict__ out) {
  __shared__ float W1l[DD * NHID];
  __shared__ float W2l[NHID * NOUT];
  __shared__ float hid[4][NHID];
  __shared__ float hrow[4][DD];
  __shared__ float uscl[DD], ushf[DD];
  for (int i = threadIdx.x; i < DD * NHID; i += 256) W1l[i] = W1[i];
  for (int i = threadIdx.x; i < NHID * NOUT; i += 256) W2l[i] = W2[i];
  if (threadIdx.x < DD) {
    uscl[threadIdx.x] = stats[384 + threadIdx.x];
    ushf[threadIdx.x] = stats[480 + threadIdx.x];
  }
  __syncthreads();
  const int w = threadIdx.x >> 6, lane = threadIdx.x & 63;
  for (int n = blockIdx.x * 4 + w; n < NN; n += gridDim.x * 4) {
    const ushort* hp = h + (size_t)n * DD;
    const ushort* up = hn + (size_t)n * DD;
    hrow[w][lane] = bfu2f(hp[lane])
        + fmaxf(fmaf(bfu2f(up[lane]), uscl[lane], ushf[lane]), 0.f);
    if (lane < DD - 64)
      hrow[w][64 + lane] = bfu2f(hp[64 + lane])
          + fmaxf(fmaf(bfu2f(up[64 + lane]), uscl[64 + lane], ushf[64 + lane]), 0.f);
    float a0 = b1[lane], a1 = b1[64 + lane];
    for (int k = 0; k < DD; k++) {
      const float x = hrow[w][k];
      a0 = fmaf(x, W1l[k * NHID + lane], a0);
      a1 = fmaf(x, W1l[k * NHID + 64 + lane], a1);
    }
    hid[w][lane] = fmaxf(a0, 0.f);
    hid[w][64 + lane] = fmaxf(a1, 0.f);
    if (lane < NOUT) {
      float o = b2[lane];
      for (int k = 0; k < NHID; k++) o = fmaf(hid[w][k], W2l[k * NOUT + lane], o);
      out[(size_t)n * NOUT + lane] = ma[n] * tanhf(o);
    }
  }
}

// ----------------------------------------------------------------------------
extern "C" void kernel_launch(void* const* d_in, const int* in_sizes, int n_in,
                              void* d_out, int out_size, void* d_ws, size_t ws_size,
                              hipStream_t stream) {
  const float* h1  = (const float*)d_in[0];
  const float* h2  = (const float*)d_in[1];
  const float* z   = (const float*)d_in[2];
  const float* ef  = (const float*)d_in[3];
  const float* ma  = (const float*)d_in[4];
  const float* Wh  = (const float*)d_in[5];
  const float* bh  = (const float*)d_in[6];
  const float* We  = (const float*)d_in[7];
  const float* be  = (const float*)d_in[8];
  const float* WA  = (const float*)d_in[9];
  const float* bA  = (const float*)d_in[10];
  const float* WB  = (const float*)d_in[11];
  const float* bB  = (const float*)d_in[12];
  const float* WC  = (const float*)d_in[13];
  const float* bC  = (const float*)d_in[14];
  const float* WD  = (const float*)d_in[15];
  const float* bD  = (const float*)d_in[16];
  const float* WE  = (const float*)d_in[17];
  const float* bE  = (const float*)d_in[18];
  const float* bn_h_g = (const float*)d_in[19];
  const float* bn_h_b = (const float*)d_in[20];
  const float* bn_e_g = (const float*)d_in[21];
  const float* bn_e_b = (const float*)d_in[22];
  const float* W1  = (const float*)d_in[23];
  const float* b1  = (const float*)d_in[24];
  const float* W2  = (const float*)d_in[25];
  const float* b2  = (const float*)d_in[26];
  const int*   src = (const int*)d_in[27];
  const int*   dst = (const int*)d_in[28];

  const size_t E_ELEMS = (size_t)EE * DD;
  const size_t N_ELEMS = (size_t)NN * DD;
  int tier;
  if (ws_size >= 455000000UL)      tier = 0;   // e bf16 + e_new bf16
  else if (ws_size >= 297000000UL) tier = 1;   // e fp8  + e_new bf16  (confirmed r5/r6)
  else                             tier = 2;   // e fp8  + e_new fp8
  const size_t esze = (tier == 0) ? 2 : 1;
  const size_t eszn = (tier <= 1) ? 2 : 1;

  char* p = (char*)d_ws;
  void* e     = (void*)p; p += E_ELEMS * esze;
  void* e_new = (void*)p; p += E_ELEMS * eszn;
  ushort* h   = (ushort*)p; p += N_ELEMS * 2;
  ushort* hn  = (ushort*)p; p += N_ELEMS * 2;
  ushort* Bhb = (ushort*)p; p += N_ELEMS * 2;
  ushort* Dhb = (ushort*)p; p += N_ELEMS * 2;
  ushort* Ehb = (ushort*)p; p += N_ELEMS * 2;
  int* cnt    = (int*)p; p += (size_t)NN * 4;
  int* rowptr = (int*)p; p += (size_t)(NN + 1) * 4;
  int* cursor = (int*)p; p += (size_t)NN * 4;
  int* perm   = (int*)p; p += (size_t)EE * 4;
  int* srcC   = (int*)p; p += (size_t)EE * 4;
  int* dstC   = (int*)p; p += (size_t)EE * 4;
  float* stats = (float*)p;

  k_zero_init<<<64, 256, 0, stream>>>(cnt, stats);
  k_hist<<<3125, 256, 0, stream>>>(dst, cnt);
  k_scan<<<1, 256, 0, stream>>>(cnt, rowptr, cursor);
  k_scatter<<<3125, 256, 0, stream>>>(src, dst, cursor, perm, srcC, dstC);
  k_embed_h<<<1024, 256, 0, stream>>>(h1, h2, z, Wh, bh, h);
  if (esze == 2) k_embed_e<2><<<2048, 256, 0, stream>>>(ef, We, be, perm, e);
  else           k_embed_e<1><<<2048, 256, 0, stream>>>(ef, We, be, perm, e);

  for (int l = 0; l < 4; l++) {
#define NG_ARGS h, WA + l*DD*DD, WB + l*DD*DD, WD + l*DD*DD, WE + l*DD*DD, \
    bA + l*DD, bB + l*DD, bD + l*DD, bE + l*DD, hn, Bhb, Dhb, Ehb, stats
    if (l == 0) k_ngemm<0><<<391, 256, 0, stream>>>(NG_ARGS);
    else        k_ngemm<1><<<391, 256, 0, stream>>>(NG_ARGS);
#undef NG_ARGS
    const float* WCl = WC + l * DD * DD;
    const float* bCl = bC + l * DD;
#define EDGE_ARGS e, e_new, WCl, bCl, Dhb, Ehb, srcC, dstC, stats
    if (tier == 0) {
      if (l == 0)      k_edge<0,2,2><<<1250, 256, 0, stream>>>(EDGE_ARGS);
      else if (l < 3)  k_edge<1,2,2><<<1250, 256, 0, stream>>>(EDGE_ARGS);
      else             k_edge<2,2,2><<<1250, 256, 0, stream>>>(EDGE_ARGS);
    } else if (tier == 1) {
      if (l == 0)      k_edge<0,1,2><<<1250, 256, 0, stream>>>(EDGE_ARGS);
      else if (l < 3)  k_edge<1,1,2><<<1250, 256, 0, stream>>>(EDGE_ARGS);
      else             k_edge<2,1,2><<<1250, 256, 0, stream>>>(EDGE_ARGS);
    } else {
      if (l == 0)      k_edge<0,1,1><<<1250, 256, 0, stream>>>(EDGE_ARGS);
      else if (l < 3)  k_edge<1,1,1><<<1250, 256, 0, stream>>>(EDGE_ARGS);
      else             k_edge<2,1,1><<<1250, 256, 0, stream>>>(EDGE_ARGS);
    }
#undef EDGE_ARGS
    if (eszn == 2) k_agg<2><<<1024, 256, 0, stream>>>(e_new, srcC, rowptr, Bhb, hn, stats);
    else           k_agg<1><<<1024, 256, 0, stream>>>(e_new, srcC, rowptr, Bhb, hn, stats);
    k_finalize<<<1, 128, 0, stream>>>(stats,
        bn_h_g + l * DD, bn_h_b + l * DD, bn_e_g + l * DD, bn_e_b + l * DD);
  }

  k_head<<<1024, 256, 0, stream>>>(h, hn, stats, W1, b1, W2, b2, ma, (float*)d_out);
}

// Round 9
// 1856.080 us; speedup vs baseline: 1.5889x; 1.0573x over previous
//
#include <hip/hip_runtime.h>
#include <math.h>

#define NN 50000
#define EE 800000
#define DD 96
#define NHID 128
#define NOUT 8
#define LDA 104   // padded LDS row stride in bf16 elems (208 B; 16B-aligned)

typedef unsigned int uint32;
typedef float floatx2 __attribute__((ext_vector_type(2)));
typedef float f32x4 __attribute__((ext_vector_type(4)));
typedef short bf16x8 __attribute__((ext_vector_type(8)));

__device__ __forceinline__ float bfu2f(ushort u) {
  union { uint32 u; float f; } v; v.u = ((uint32)u) << 16; return v.f;
}
__device__ __forceinline__ ushort f2bf(float x) {
  union { float f; uint32 u; } v; v.f = x;
  uint32 r = (v.u + 0x7fffu + ((v.u >> 16) & 1u)) >> 16;
  return (ushort)r;
}

// Edge storage traits: 2 -> bf16, 1 -> fp8 e4m3 (OCP, HW cvt). Index: group of 4 channels.
template <int ESZ> struct EST;
template <> struct EST<2> {
  typedef ushort4 Raw;
  static __device__ __forceinline__ Raw ldraw(const void* e, size_t grp) {
    return ((const ushort4*)e)[grp];
  }
  static __device__ __forceinline__ float4 dec(Raw a) {
    return make_float4(bfu2f(a.x), bfu2f(a.y), bfu2f(a.z), bfu2f(a.w));
  }
  static __device__ __forceinline__ float4 ld(const void* e, size_t grp) {
    return dec(ldraw(e, grp));
  }
  static __device__ __forceinline__ void st(void* e, size_t grp, float4 v) {
    ushort4 o; o.x = f2bf(v.x); o.y = f2bf(v.y); o.z = f2bf(v.z); o.w = f2bf(v.w);
    ((ushort4*)e)[grp] = o;
  }
  static __device__ __forceinline__ float ld1c(const void* e, size_t pos, int c) {
    return bfu2f(((const ushort*)e)[pos * DD + c]);
  }
};
template <> struct EST<1> {
  typedef int Raw;
  static __device__ __forceinline__ Raw ldraw(const void* e, size_t grp) {
    return ((const int*)e)[grp];
  }
  static __device__ __forceinline__ float4 dec(Raw u) {
    floatx2 lo = __builtin_amdgcn_cvt_pk_f32_fp8(u, false);
    floatx2 hi = __builtin_amdgcn_cvt_pk_f32_fp8(u, true);
    return make_float4(lo[0], lo[1], hi[0], hi[1]);
  }
  static __device__ __forceinline__ float4 ld(const void* e, size_t grp) {
    return dec(ldraw(e, grp));
  }
  static __device__ __forceinline__ void st(void* e, size_t grp, float4 v) {
    int u = 0;
    u = __builtin_amdgcn_cvt_pk_fp8_f32(v.x, v.y, u, false);
    u = __builtin_amdgcn_cvt_pk_fp8_f32(v.z, v.w, u, true);
    ((int*)e)[grp] = u;
  }
  static __device__ __forceinline__ float ld1c(const void* e, size_t pos, int c) {
    const int dw = ((const int*)e)[pos * (DD / 4) + (c >> 2)];
    floatx2 lo = __builtin_amdgcn_cvt_pk_f32_fp8(dw, false);
    floatx2 hi = __builtin_amdgcn_cvt_pk_f32_fp8(dw, true);
    return (c & 2) ? ((c & 1) ? hi[1] : hi[0]) : ((c & 1) ? lo[1] : lo[0]);
  }
};

// ------------------------------------------------------------- init / CSR build
__global__ __launch_bounds__(256) void k_zero_init(int* __restrict__ cnt,
    float* __restrict__ stats) {
  int i = blockIdx.x * 256 + threadIdx.x;
  const int str = gridDim.x * 256;
  for (; i < NN; i += str) cnt[i] = 0;
  if (blockIdx.x == 0)
    for (int j = threadIdx.x; j < 768; j += 256) stats[j] = 0.f;
}

__global__ __launch_bounds__(256) void k_hist(const int* __restrict__ dst,
    int* __restrict__ cnt) {
  const int i = blockIdx.x * 256 + threadIdx.x;
  if (i < EE) atomicAdd(&cnt[dst[i]], 1);
}

__global__ __launch_bounds__(256) void k_scan(const int* __restrict__ cnt,
    int* __restrict__ rowptr, int* __restrict__ cursor) {
  __shared__ int part[256];
  const int t = threadIdx.x;
  const int CH = (NN + 255) / 256;
  const int lo = t * CH, hi = min((t + 1) * CH, NN);
  int s = 0;
  for (int i = lo; i < hi; i++) s += cnt[i];
  part[t] = s;
  __syncthreads();
  for (int off = 1; off < 256; off <<= 1) {
    int v = (t >= off) ? part[t - off] : 0;
    __syncthreads();
    part[t] += v;
    __syncthreads();
  }
  int base = (t == 0) ? 0 : part[t - 1];
  for (int i = lo; i < hi; i++) {
    rowptr[i] = base; cursor[i] = base; base += cnt[i];
  }
  if (t == 255) rowptr[NN] = base;
}

__global__ __launch_bounds__(256) void k_scatter(const int* __restrict__ src,
    const int* __restrict__ dst, int* __restrict__ cursor,
    int* __restrict__ perm, int* __restrict__ srcC, int* __restrict__ dstC) {
  const int i = blockIdx.x * 256 + threadIdx.x;
  if (i < EE) {
    const int d = dst[i];
    const int pos = atomicAdd(&cursor[d], 1);
    perm[pos] = i; srcC[pos] = src[i]; dstC[pos] = d;
  }
}

// ---------------------------------------------------------------- embeddings
__global__ __launch_bounds__(256) void k_embed_h(const float* __restrict__ h1,
    const float* __restrict__ h2, const float* __restrict__ z,
    const float* __restrict__ W, const float* __restrict__ b,
    ushort* __restrict__ h) {
  int idx = blockIdx.x * 256 + threadIdx.x;
  const int total = NN * DD;
  const int stride = gridDim.x * 256;
  for (; idx < total; idx += stride) {
    int n = idx / DD, c = idx - n * DD;
    float acc = b[c];
#pragma unroll
    for (int k = 0; k < 6; k++)  acc = fmaf(h1[n * 6 + k], W[k * DD + c], acc);
#pragma unroll
    for (int k = 0; k < 4; k++)  acc = fmaf(h2[n * 4 + k], W[(6 + k) * DD + c], acc);
#pragma unroll
    for (int k = 0; k < 16; k++) acc = fmaf(z[n * 16 + k], W[(10 + k) * DD + c], acc);
    h[idx] = f2bf(acc);
  }
}

template <int EZ>
__global__ __launch_bounds__(256) void k_embed_e(const float* __restrict__ ef,
    const float* __restrict__ W, const float* __restrict__ b,
    const int* __restrict__ perm, void* __restrict__ e) {
  int g = blockIdx.x * 256 + threadIdx.x;
  const int totalg = EE * (DD / 4);
  const int stride = gridDim.x * 256;
  for (; g < totalg; g += stride) {
    const int pos = g / 24, cg = (g - pos * 24) * 4;
    const int orig = perm[pos];
    const float f0 = ef[orig * 4], f1 = ef[orig * 4 + 1];
    const float f2 = ef[orig * 4 + 2], f3 = ef[orig * 4 + 3];
    float4 acc;
    acc.x = b[cg+0] + f0*W[cg+0] + f1*W[DD+cg+0] + f2*W[2*DD+cg+0] + f3*W[3*DD+cg+0];
    acc.y = b[cg+1] + f0*W[cg+1] + f1*W[DD+cg+1] + f2*W[2*DD+cg+1] + f3*W[3*DD+cg+1];
    acc.z = b[cg+2] + f0*W[cg+2] + f1*W[DD+cg+2] + f2*W[2*DD+cg+2] + f3*W[3*DD+cg+2];
    acc.w = b[cg+3] + f0*W[cg+3] + f1*W[DD+cg+3] + f2*W[2*DD+cg+3] + f3*W[3*DD+cg+3];
    EST<EZ>::st(e, g, acc);
  }
}

// ---------------- node GEMMs via MFMA: one block = 128 rows x all 4 matrices,
//                  with fused lazy h-update (h += relu(BN(hn)) from prev layer).
template <int LAZY>
__global__ __launch_bounds__(256) void k_ngemm(ushort* __restrict__ h,
    const float* __restrict__ WAp, const float* __restrict__ WBp,
    const float* __restrict__ WDp, const float* __restrict__ WEp,
    const float* __restrict__ bAp, const float* __restrict__ bBp,
    const float* __restrict__ bDp, const float* __restrict__ bEp,
    ushort* __restrict__ oA, ushort* __restrict__ oB,
    ushort* __restrict__ oD, ushort* __restrict__ oE,
    const float* __restrict__ stats) {
  __shared__ __align__(16) ushort Wt[DD * LDA];
  __shared__ __align__(16) ushort At[128 * LDA];
  __shared__ float uscl[DD], ushf[DD];
  const int tid = threadIdx.x;
  if (LAZY && tid < DD) { uscl[tid] = stats[384 + tid]; ushf[tid] = stats[480 + tid]; }
  if (LAZY) __syncthreads();
  const int base = blockIdx.x * 128;
#pragma unroll
  for (int ii = 0; ii < 12; ii++) {
    const int i = ii * 256 + tid;
    const int r = i / 24, q = i - (i / 24) * 24;
    const int row = base + r;
    ushort4 a; a.x = 0; a.y = 0; a.z = 0; a.w = 0;
    if (row < NN) a = ((const ushort4*)h)[(size_t)row * 24 + q];
    if (LAZY && row < NN) {
      const ushort4 u = ((const ushort4*)oA)[(size_t)row * 24 + q];  // oA == hn
      const int c = q * 4;
      float f0 = bfu2f(a.x) + fmaxf(fmaf(bfu2f(u.x), uscl[c],     ushf[c]),     0.f);
      float f1 = bfu2f(a.y) + fmaxf(fmaf(bfu2f(u.y), uscl[c + 1], ushf[c + 1]), 0.f);
      float f2 = bfu2f(a.z) + fmaxf(fmaf(bfu2f(u.z), uscl[c + 2], ushf[c + 2]), 0.f);
      float f3 = bfu2f(a.w) + fmaxf(fmaf(bfu2f(u.w), uscl[c + 3], ushf[c + 3]), 0.f);
      a.x = f2bf(f0); a.y = f2bf(f1); a.z = f2bf(f2); a.w = f2bf(f3);
      ((ushort4*)h)[(size_t)row * 24 + q] = a;
    }
    *(ushort4*)&At[r * LDA + q * 4] = a;
  }
  const int w = tid >> 6, lane = tid & 63;
  const int lrow = lane & 15, lgrp = lane >> 4;
#pragma unroll
  for (int m = 0; m < 4; m++) {
    const float* W  = (m == 0) ? WAp : (m == 1) ? WBp : (m == 2) ? WDp : WEp;
    const float* bi = (m == 0) ? bAp : (m == 1) ? bBp : (m == 2) ? bDp : bEp;
    ushort* out     = (m == 0) ? oA  : (m == 1) ? oB  : (m == 2) ? oD  : oE;
#pragma unroll
    for (int ii = 0; ii < 36; ii++) {
      const int i = ii * 256 + tid;
      const int k = i / DD, n = i - (i / DD) * DD;
      Wt[n * LDA + k] = f2bf(W[i]);
    }
    __syncthreads();
    f32x4 acc[2][6];
#pragma unroll
    for (int rt2 = 0; rt2 < 2; rt2++)
#pragma unroll
      for (int nt = 0; nt < 6; nt++) {
        acc[rt2][nt][0] = 0.f; acc[rt2][nt][1] = 0.f;
        acc[rt2][nt][2] = 0.f; acc[rt2][nt][3] = 0.f;
      }
#pragma unroll
    for (int rt2 = 0; rt2 < 2; rt2++) {
      const int rt = w * 2 + rt2;
#pragma unroll
      for (int kk = 0; kk < 3; kk++) {
        const bf16x8 af = *(const bf16x8*)&At[(rt * 16 + lrow) * LDA + kk * 32 + lgrp * 8];
#pragma unroll
        for (int nt = 0; nt < 6; nt++) {
          const bf16x8 bfr = *(const bf16x8*)&Wt[(nt * 16 + lrow) * LDA + kk * 32 + lgrp * 8];
          acc[rt2][nt] = __builtin_amdgcn_mfma_f32_16x16x32_bf16(af, bfr, acc[rt2][nt], 0, 0, 0);
        }
      }
    }
#pragma unroll
    for (int rt2 = 0; rt2 < 2; rt2++) {
      const int rt = w * 2 + rt2;
#pragma unroll
      for (int j = 0; j < 4; j++) {
        const int row = base + rt * 16 + lgrp * 4 + j;
        if (row < NN) {
#pragma unroll
          for (int nt = 0; nt < 6; nt++) {
            const int ch = nt * 16 + lrow;
            out[(size_t)row * DD + ch] = f2bf(acc[rt2][nt][j] + bi[ch]);
          }
        }
      }
    }
    __syncthreads();
  }
}

// ---------------- edge kernel with T14 async-stage: prefetch next tile's e/e_new
//                  into REGISTERS during current tile's MFMA+epilogue.
// MODE 0: layer 0. MODE 1: apply pending BN-e update, write e back. MODE 2: no write-back.
template <int MODE, int EZE, int EZN>
__global__ __launch_bounds__(256) void k_edge(void* __restrict__ e,
    void* __restrict__ e_new,
    const float* __restrict__ WC, const float* __restrict__ bC,
    const ushort* __restrict__ Dh, const ushort* __restrict__ Eh,
    const int* __restrict__ srcC, const int* __restrict__ dstC,
    float* __restrict__ stats) {
  __shared__ __align__(16) ushort Wt[DD * LDA];
  __shared__ __align__(16) ushort At[64 * LDA];
  __shared__ float sred[2 * DD];
  __shared__ float escl[DD], eshl[DD];
  __shared__ int sidx_s[64], sidx_d[64];
  const int tid = threadIdx.x;
  for (int i = tid; i < DD * DD; i += 256) {
    const int k = i / DD, n = i - (i / DD) * DD;
    Wt[n * LDA + k] = f2bf(WC[i]);
  }
  if (tid < 2 * DD) sred[tid] = 0.f;
  if (MODE >= 1 && tid < DD) { escl[tid] = stats[576 + tid]; eshl[tid] = stats[672 + tid]; }
  __syncthreads();
  const int w = tid >> 6, lane = tid & 63;
  const int lrow = lane & 15, lgrp = lane >> 4;
  const int qq0 = lane % 24;
  const int qq1 = (lane + 16) % 24;
  const int qq2 = (lane + 8) % 24;
  const float4 bc0 = *(const float4*)&bC[qq0 * 4];
  const float4 bc1 = *(const float4*)&bC[qq1 * 4];
  const float4 bc2 = *(const float4*)&bC[qq2 * 4];
  float sacc0[4] = {0,0,0,0}, sacc1[4] = {0,0,0,0}, sacc2[4] = {0,0,0,0};
  float qacc0[4] = {0,0,0,0}, qacc1[4] = {0,0,0,0}, qacc2[4] = {0,0,0,0};

  const int NT = EE / 64;   // 12500
  typename EST<EZE>::Raw pe[6];
  typename EST<EZN>::Raw pn[6];
  int ps = 0, pd = 0;
  // ---- prologue prefetch (blockIdx.x < gridDim.x <= NT always)
  {
    const size_t b24 = (size_t)blockIdx.x * 64 * 24;
#pragma unroll
    for (int ii = 0; ii < 6; ii++) {
      const int i = ii * 256 + tid;
      pe[ii] = EST<EZE>::ldraw(e, b24 + i);
      if (MODE >= 1) pn[ii] = EST<EZN>::ldraw(e_new, b24 + i);
    }
    if (tid < 64) {
      ps = srcC[blockIdx.x * 64 + tid];
      pd = dstC[blockIdx.x * 64 + tid];
    }
  }
  for (int t = blockIdx.x; t < NT; t += gridDim.x) {
    const size_t base = (size_t)t * 64;
    const size_t b24 = base * 24;
    // ---- W phase: consume prefetched regs -> At (+ lazy update, e write-back)
#pragma unroll
    for (int ii = 0; ii < 6; ii++) {
      const int i = ii * 256 + tid;
      const int r = i / 24, gq = i - (i / 24) * 24;
      float4 a = EST<EZE>::dec(pe[ii]);
      if (MODE >= 1) {
        const float4 d = EST<EZN>::dec(pn[ii]);
        const int c = gq * 4;
        a.x += fmaxf(fmaf(d.x, escl[c],     eshl[c]),     0.f);
        a.y += fmaxf(fmaf(d.y, escl[c + 1], eshl[c + 1]), 0.f);
        a.z += fmaxf(fmaf(d.z, escl[c + 2], eshl[c + 2]), 0.f);
        a.w += fmaxf(fmaf(d.w, escl[c + 3], eshl[c + 3]), 0.f);
        if (MODE == 1) EST<EZE>::st(e, b24 + i, a);
      }
      ushort4 o; o.x = f2bf(a.x); o.y = f2bf(a.y); o.z = f2bf(a.z); o.w = f2bf(a.w);
      *(ushort4*)&At[r * LDA + gq * 4] = o;
    }
    if (tid < 64) { sidx_s[tid] = ps; sidx_d[tid] = pd; }
    // ---- R phase: issue next tile's loads (overlap with MFMA+epilogue below)
    const int tn = t + gridDim.x;
    if (tn < NT) {
      const size_t bn = (size_t)tn * 64 * 24;
#pragma unroll
      for (int ii = 0; ii < 6; ii++) {
        const int i = ii * 256 + tid;
        pe[ii] = EST<EZE>::ldraw(e, bn + i);
        if (MODE >= 1) pn[ii] = EST<EZN>::ldraw(e_new, bn + i);
      }
      if (tid < 64) { ps = srcC[tn * 64 + tid]; pd = dstC[tn * 64 + tid]; }
    }
    __syncthreads();   // At + sidx visible to all waves
    // ---- MFMA
    f32x4 acc[6];
#pragma unroll
    for (int nt = 0; nt < 6; nt++) { acc[nt][0]=0.f; acc[nt][1]=0.f; acc[nt][2]=0.f; acc[nt][3]=0.f; }
#pragma unroll
    for (int kk = 0; kk < 3; kk++) {
      const bf16x8 af = *(const bf16x8*)&At[(w * 16 + lrow) * LDA + kk * 32 + lgrp * 8];
#pragma unroll
      for (int nt = 0; nt < 6; nt++) {
        const bf16x8 bfr = *(const bf16x8*)&Wt[(nt * 16 + lrow) * LDA + kk * 32 + lgrp * 8];
        acc[nt] = __builtin_amdgcn_mfma_f32_16x16x32_bf16(af, bfr, acc[nt], 0, 0, 0);
      }
    }
    // ---- acc -> At (bf16), wave-local rows
#pragma unroll
    for (int j = 0; j < 4; j++) {
#pragma unroll
      for (int nt = 0; nt < 6; nt++) {
        At[(w * 16 + lgrp * 4 + j) * LDA + nt * 16 + lrow] = f2bf(acc[nt][j]);
      }
    }
    // ---- epilogue: row-major vectorized
#pragma unroll
    for (int it = 0; it < 6; it++) {
      const int idx = it * 64 + lane;
      const int r16 = idx / 24, gq = idx - (idx / 24) * 24;
      const int row = w * 16 + r16;
      const size_t pos = base + row;
      const int s = sidx_s[row], d2 = sidx_d[row];
      const ushort4 av = *(const ushort4*)&At[row * LDA + gq * 4];
      const ushort4 dv = *(const ushort4*)&Dh[(size_t)s * DD + gq * 4];
      const ushort4 ev = *(const ushort4*)&Eh[(size_t)d2 * DD + gq * 4];
      const float4 bc = (it % 3 == 0) ? bc0 : (it % 3 == 1) ? bc1 : bc2;
      float4 v;
      v.x = bfu2f(av.x) + bc.x + bfu2f(dv.x) + bfu2f(ev.x);
      v.y = bfu2f(av.y) + bc.y + bfu2f(dv.y) + bfu2f(ev.y);
      v.z = bfu2f(av.z) + bc.z + bfu2f(dv.z) + bfu2f(ev.z);
      v.w = bfu2f(av.w) + bc.w + bfu2f(dv.w) + bfu2f(ev.w);
      if (it % 3 == 0) {
        sacc0[0]+=v.x; sacc0[1]+=v.y; sacc0[2]+=v.z; sacc0[3]+=v.w;
        qacc0[0]+=v.x*v.x; qacc0[1]+=v.y*v.y; qacc0[2]+=v.z*v.z; qacc0[3]+=v.w*v.w;
      } else if (it % 3 == 1) {
        sacc1[0]+=v.x; sacc1[1]+=v.y; sacc1[2]+=v.z; sacc1[3]+=v.w;
        qacc1[0]+=v.x*v.x; qacc1[1]+=v.y*v.y; qacc1[2]+=v.z*v.z; qacc1[3]+=v.w*v.w;
      } else {
        sacc2[0]+=v.x; sacc2[1]+=v.y; sacc2[2]+=v.z; sacc2[3]+=v.w;
        qacc2[0]+=v.x*v.x; qacc2[1]+=v.y*v.y; qacc2[2]+=v.z*v.z; qacc2[3]+=v.w*v.w;
      }
      EST<EZN>::st(e_new, pos * 24 + gq, v);
    }
    __syncthreads();   // At free for next W phase
  }
#pragma unroll
  for (int c = 0; c < 4; c++) {
    atomicAdd(&sred[qq0 * 4 + c], sacc0[c]);
    atomicAdd(&sred[DD + qq0 * 4 + c], qacc0[c]);
    atomicAdd(&sred[qq1 * 4 + c], sacc1[c]);
    atomicAdd(&sred[DD + qq1 * 4 + c], qacc1[c]);
    atomicAdd(&sred[qq2 * 4 + c], sacc2[c]);
    atomicAdd(&sred[DD + qq2 * 4 + c], qacc2[c]);
  }
  __syncthreads();
  if (tid < 2 * DD) atomicAdd(&stats[tid], sred[tid]);
}

// ---------------- CSR aggregation: num/den in registers, hn = Ah + num/(den+eps),
//                  BN-h stats. Half-wave per node; 2-way edge unroll.
template <int EZN>
__global__ __launch_bounds__(256) void k_agg(const void* __restrict__ e_new,
    const int* __restrict__ srcC, const int* __restrict__ rowptr,
    const ushort* __restrict__ Bh, ushort* __restrict__ hn,
    float* __restrict__ stats) {
  __shared__ float sred[2 * DD];
  if (threadIdx.x < 2 * DD) sred[threadIdx.x] = 0.f;
  __syncthreads();
  const int hw = threadIdx.x >> 5, lane = threadIdx.x & 31;
  const int c0 = lane, c1 = lane + 32, c2 = lane + 64;
  float sa0 = 0, sa1 = 0, sa2 = 0, qa0 = 0, qa1 = 0, qa2 = 0;
  for (int n = blockIdx.x * 8 + hw; n < NN; n += gridDim.x * 8) {
    const int rs = rowptr[n], re = rowptr[n + 1];
    float n0 = 0, n1 = 0, n2 = 0, d0 = 0, d1 = 0, d2 = 0;
    int p = rs;
    for (; p + 2 <= re; p += 2) {
      const int sA = srcC[p], sB = srcC[p + 1];
      const float vA0 = EST<EZN>::ld1c(e_new, (size_t)p, c0);
      const float vA1 = EST<EZN>::ld1c(e_new, (size_t)p, c1);
      const float vA2 = EST<EZN>::ld1c(e_new, (size_t)p, c2);
      const float vB0 = EST<EZN>::ld1c(e_new, (size_t)(p + 1), c0);
      const float vB1 = EST<EZN>::ld1c(e_new, (size_t)(p + 1), c1);
      const float vB2 = EST<EZN>::ld1c(e_new, (size_t)(p + 1), c2);
      const size_t sbA = (size_t)sA * DD, sbB = (size_t)sB * DD;
      const float bA0 = bfu2f(Bh[sbA + c0]), bA1 = bfu2f(Bh[sbA + c1]), bA2 = bfu2f(Bh[sbA + c2]);
      const float bB0 = bfu2f(Bh[sbB + c0]), bB1 = bfu2f(Bh[sbB + c1]), bB2 = bfu2f(Bh[sbB + c2]);
      const float gA0 = 1.f / (1.f + __expf(-vA0));
      const float gA1 = 1.f / (1.f + __expf(-vA1));
      const float gA2 = 1.f / (1.f + __expf(-vA2));
      const float gB0 = 1.f / (1.f + __expf(-vB0));
      const float gB1 = 1.f / (1.f + __expf(-vB1));
      const float gB2 = 1.f / (1.f + __expf(-vB2));
      n0 += gA0 * bA0 + gB0 * bB0; d0 += gA0 + gB0;
      n1 += gA1 * bA1 + gB1 * bB1; d1 += gA1 + gB1;
      n2 += gA2 * bA2 + gB2 * bB2; d2 += gA2 + gB2;
    }
    if (p < re) {
      const int s = srcC[p];
      const float v0 = EST<EZN>::ld1c(e_new, (size_t)p, c0);
      const float v1 = EST<EZN>::ld1c(e_new, (size_t)p, c1);
      const float v2 = EST<EZN>::ld1c(e_new, (size_t)p, c2);
      const float g0 = 1.f / (1.f + __expf(-v0));
      const float g1 = 1.f / (1.f + __expf(-v1));
      const float g2 = 1.f / (1.f + __expf(-v2));
      const size_t sb = (size_t)s * DD;
      n0 += g0 * bfu2f(Bh[sb + c0]); d0 += g0;
      n1 += g1 * bfu2f(Bh[sb + c1]); d1 += g1;
      n2 += g2 * bfu2f(Bh[sb + c2]); d2 += g2;
    }
    const size_t hb = (size_t)n * DD;
    const float v0 = bfu2f(hn[hb + c0]) + n0 / (d0 + 1e-6f);
    const float v1 = bfu2f(hn[hb + c1]) + n1 / (d1 + 1e-6f);
    const float v2 = bfu2f(hn[hb + c2]) + n2 / (d2 + 1e-6f);
    hn[hb + c0] = f2bf(v0); hn[hb + c1] = f2bf(v1); hn[hb + c2] = f2bf(v2);
    sa0 += v0; qa0 += v0 * v0;
    sa1 += v1; qa1 += v1 * v1;
    sa2 += v2; qa2 += v2 * v2;
  }
  atomicAdd(&sred[c0], sa0); atomicAdd(&sred[c1], sa1); atomicAdd(&sred[c2], sa2);
  atomicAdd(&sred[DD + c0], qa0); atomicAdd(&sred[DD + c1], qa1); atomicAdd(&sred[DD + c2], qa2);
  __syncthreads();
  if (threadIdx.x < 2 * DD) atomicAdd(&stats[192 + threadIdx.x], sred[threadIdx.x]);
}

// ---------------- finalize BN stats -> scale/shift; zero raw slots for next layer
__global__ void k_finalize(float* __restrict__ stats,
    const float* __restrict__ g_h, const float* __restrict__ b_h,
    const float* __restrict__ g_e, const float* __restrict__ b_e) {
  const int c = threadIdx.x;
  if (c < DD) {
    const float mu_h = stats[192 + c] / (float)NN;
    const float var_h = stats[288 + c] / (float)NN - mu_h * mu_h;
    const float sc_h = g_h[c] * rsqrtf(var_h + 1e-5f);
    const float mu_e = stats[c] / (float)EE;
    const float var_e = stats[96 + c] / (float)EE - mu_e * mu_e;
    const float sc_e = g_e[c] * rsqrtf(var_e + 1e-5f);
    stats[384 + c] = sc_h;
    stats[480 + c] = b_h[c] - mu_h * sc_h;
    stats[576 + c] = sc_e;
    stats[672 + c] = b_e[c] - mu_e * sc_e;
    stats[c] = 0.f; stats[96 + c] = 0.f; stats[192 + c] = 0.f; stats[288 + c] = 0.f;
  }
}

// ------------------------- MLP head with fused final h-update (layer-3 BN-h)
__global__ __launch_bounds__(256) void k_head(const ushort* __restrict__ h,
    const ushort* __restrict__ hn, const float* __restrict__ stats,
    const float* __restrict__ W1, const float* __restrict__ b1,
    const float* __restrict__ W2, const float* __restrict__ b2,
    const float* __restrict__ ma, float* __restrict__ out) {
  __shared__ float W1l[DD * NHID];
  __shared__ float W2l[NHID * NOUT];
  __shared__ float hid[4][NHID];
  __shared__ float hrow[4][DD];
  __shared__ float uscl[DD], ushf[DD];
  for (int i = threadIdx.x; i < DD * NHID; i += 256) W1l[i] = W1[i];
  for (int i = threadIdx.x; i < NHID * NOUT; i += 256) W2l[i] = W2[i];
  if (threadIdx.x < DD) {
    uscl[threadIdx.x] = stats[384 + threadIdx.x];
    ushf[threadIdx.x] = stats[480 + threadIdx.x];
  }
  __syncthreads();
  const int w = threadIdx.x >> 6, lane = threadIdx.x & 63;
  for (int n = blockIdx.x * 4 + w; n < NN; n += gridDim.x * 4) {
    const ushort* hp = h + (size_t)n * DD;
    const ushort* up = hn + (size_t)n * DD;
    hrow[w][lane] = bfu2f(hp[lane])
        + fmaxf(fmaf(bfu2f(up[lane]), uscl[lane], ushf[lane]), 0.f);
    if (lane < DD - 64)
      hrow[w][64 + lane] = bfu2f(hp[64 + lane])
          + fmaxf(fmaf(bfu2f(up[64 + lane]), uscl[64 + lane], ushf[64 + lane]), 0.f);
    float a0 = b1[lane], a1 = b1[64 + lane];
    for (int k = 0; k < DD; k++) {
      const float x = hrow[w][k];
      a0 = fmaf(x, W1l[k * NHID + lane], a0);
      a1 = fmaf(x, W1l[k * NHID + 64 + lane], a1);
    }
    hid[w][lane] = fmaxf(a0, 0.f);
    hid[w][64 + lane] = fmaxf(a1, 0.f);
    if (lane < NOUT) {
      float o = b2[lane];
      for (int k = 0; k < NHID; k++) o = fmaf(hid[w][k], W2l[k * NOUT + lane], o);
      out[(size_t)n * NOUT + lane] = ma[n] * tanhf(o);
    }
  }
}

// ----------------------------------------------------------------------------
extern "C" void kernel_launch(void* const* d_in, const int* in_sizes, int n_in,
                              void* d_out, int out_size, void* d_ws, size_t ws_size,
                              hipStream_t stream) {
  const float* h1  = (const float*)d_in[0];
  const float* h2  = (const float*)d_in[1];
  const float* z   = (const float*)d_in[2];
  const float* ef  = (const float*)d_in[3];
  const float* ma  = (const float*)d_in[4];
  const float* Wh  = (const float*)d_in[5];
  const float* bh  = (const float*)d_in[6];
  const float* We  = (const float*)d_in[7];
  const float* be  = (const float*)d_in[8];
  const float* WA  = (const float*)d_in[9];
  const float* bA  = (const float*)d_in[10];
  const float* WB  = (const float*)d_in[11];
  const float* bB  = (const float*)d_in[12];
  const float* WC  = (const float*)d_in[13];
  const float* bC  = (const float*)d_in[14];
  const float* WD  = (const float*)d_in[15];
  const float* bD  = (const float*)d_in[16];
  const float* WE  = (const float*)d_in[17];
  const float* bE  = (const float*)d_in[18];
  const float* bn_h_g = (const float*)d_in[19];
  const float* bn_h_b = (const float*)d_in[20];
  const float* bn_e_g = (const float*)d_in[21];
  const float* bn_e_b = (const float*)d_in[22];
  const float* W1  = (const float*)d_in[23];
  const float* b1  = (const float*)d_in[24];
  const float* W2  = (const float*)d_in[25];
  const float* b2  = (const float*)d_in[26];
  const int*   src = (const int*)d_in[27];
  const int*   dst = (const int*)d_in[28];

  const size_t E_ELEMS = (size_t)EE * DD;
  const size_t N_ELEMS = (size_t)NN * DD;
  int tier;
  if (ws_size >= 455000000UL)      tier = 0;   // e bf16 + e_new bf16
  else if (ws_size >= 297000000UL) tier = 1;   // e fp8  + e_new bf16  (confirmed r5-r8)
  else                             tier = 2;   // e fp8  + e_new fp8
  const size_t esze = (tier == 0) ? 2 : 1;
  const size_t eszn = (tier <= 1) ? 2 : 1;

  char* p = (char*)d_ws;
  void* e     = (void*)p; p += E_ELEMS * esze;
  void* e_new = (void*)p; p += E_ELEMS * eszn;
  ushort* h   = (ushort*)p; p += N_ELEMS * 2;
  ushort* hn  = (ushort*)p; p += N_ELEMS * 2;
  ushort* Bhb = (ushort*)p; p += N_ELEMS * 2;
  ushort* Dhb = (ushort*)p; p += N_ELEMS * 2;
  ushort* Ehb = (ushort*)p; p += N_ELEMS * 2;
  int* cnt    = (int*)p; p += (size_t)NN * 4;
  int* rowptr = (int*)p; p += (size_t)(NN + 1) * 4;
  int* cursor = (int*)p; p += (size_t)NN * 4;
  int* perm   = (int*)p; p += (size_t)EE * 4;
  int* srcC   = (int*)p; p += (size_t)EE * 4;
  int* dstC   = (int*)p; p += (size_t)EE * 4;
  float* stats = (float*)p;

  k_zero_init<<<64, 256, 0, stream>>>(cnt, stats);
  k_hist<<<3125, 256, 0, stream>>>(dst, cnt);
  k_scan<<<1, 256, 0, stream>>>(cnt, rowptr, cursor);
  k_scatter<<<3125, 256, 0, stream>>>(src, dst, cursor, perm, srcC, dstC);
  k_embed_h<<<1024, 256, 0, stream>>>(h1, h2, z, Wh, bh, h);
  if (esze == 2) k_embed_e<2><<<2048, 256, 0, stream>>>(ef, We, be, perm, e);
  else           k_embed_e<1><<<2048, 256, 0, stream>>>(ef, We, be, perm, e);

  for (int l = 0; l < 4; l++) {
#define NG_ARGS h, WA + l*DD*DD, WB + l*DD*DD, WD + l*DD*DD, WE + l*DD*DD, \
    bA + l*DD, bB + l*DD, bD + l*DD, bE + l*DD, hn, Bhb, Dhb, Ehb, stats
    if (l == 0) k_ngemm<0><<<391, 256, 0, stream>>>(NG_ARGS);
    else        k_ngemm<1><<<391, 256, 0, stream>>>(NG_ARGS);
#undef NG_ARGS
    const float* WCl = WC + l * DD * DD;
    const float* bCl = bC + l * DD;
#define EDGE_ARGS e, e_new, WCl, bCl, Dhb, Ehb, srcC, dstC, stats
    if (tier == 0) {
      if (l == 0)      k_edge<0,2,2><<<1250, 256, 0, stream>>>(EDGE_ARGS);
      else if (l < 3)  k_edge<1,2,2><<<1250, 256, 0, stream>>>(EDGE_ARGS);
      else             k_edge<2,2,2><<<1250, 256, 0, stream>>>(EDGE_ARGS);
    } else if (tier == 1) {
      if (l == 0)      k_edge<0,1,2><<<1250, 256, 0, stream>>>(EDGE_ARGS);
      else if (l < 3)  k_edge<1,1,2><<<1250, 256, 0, stream>>>(EDGE_ARGS);
      else             k_edge<2,1,2><<<1250, 256, 0, stream>>>(EDGE_ARGS);
    } else {
      if (l == 0)      k_edge<0,1,1><<<1250, 256, 0, stream>>>(EDGE_ARGS);
      else if (l < 3)  k_edge<1,1,1><<<1250, 256, 0, stream>>>(EDGE_ARGS);
      else             k_edge<2,1,1><<<1250, 256, 0, stream>>>(EDGE_ARGS);
    }
#undef EDGE_ARGS
    if (eszn == 2) k_agg<2><<<1024, 256, 0, stream>>>(e_new, srcC, rowptr, Bhb, hn, stats);
    else           k_agg<1><<<1024, 256, 0, stream>>>(e_new, srcC, rowptr, Bhb, hn, stats);
    k_finalize<<<1, 128, 0, stream>>>(stats,
        bn_h_g + l * DD, bn_h_b + l * DD, bn_e_g + l * DD, bn_e_b + l * DD);
  }

  k_head<<<1024, 256, 0, stream>>>(h, hn, stats, W1, b1, W2, b2, ma, (float*)d_out);
}

// Round 10
// 1850.038 us; speedup vs baseline: 1.5941x; 1.0033x over previous
//
#include <hip/hip_runtime.h>
#include <math.h>

#define NN 50000
#define EE 800000
#define DD 96
#define NHID 128
#define NOUT 8
#define LDA 104   // padded LDS row stride in bf16 elems (208 B; 16B-aligned)

typedef unsigned int uint32;
typedef float floatx2 __attribute__((ext_vector_type(2)));
typedef float f32x4 __attribute__((ext_vector_type(4)));
typedef short bf16x8 __attribute__((ext_vector_type(8)));

__device__ __forceinline__ float bfu2f(ushort u) {
  union { uint32 u; float f; } v; v.u = ((uint32)u) << 16; return v.f;
}
__device__ __forceinline__ ushort f2bf(float x) {
  union { float f; uint32 u; } v; v.f = x;
  uint32 r = (v.u + 0x7fffu + ((v.u >> 16) & 1u)) >> 16;
  return (ushort)r;
}

// Edge storage traits: 2 -> bf16, 1 -> fp8 e4m3 (OCP, HW cvt). Index: group of 4 channels.
template <int ESZ> struct EST;
template <> struct EST<2> {
  typedef ushort4 Raw;
  static __device__ __forceinline__ Raw ldraw(const void* e, size_t grp) {
    return ((const ushort4*)e)[grp];
  }
  static __device__ __forceinline__ float4 dec(Raw a) {
    return make_float4(bfu2f(a.x), bfu2f(a.y), bfu2f(a.z), bfu2f(a.w));
  }
  static __device__ __forceinline__ float4 ld(const void* e, size_t grp) {
    return dec(ldraw(e, grp));
  }
  static __device__ __forceinline__ void st(void* e, size_t grp, float4 v) {
    ushort4 o; o.x = f2bf(v.x); o.y = f2bf(v.y); o.z = f2bf(v.z); o.w = f2bf(v.w);
    ((ushort4*)e)[grp] = o;
  }
  static __device__ __forceinline__ float ld1c(const void* e, size_t pos, int c) {
    return bfu2f(((const ushort*)e)[pos * DD + c]);
  }
};
template <> struct EST<1> {
  typedef int Raw;
  static __device__ __forceinline__ Raw ldraw(const void* e, size_t grp) {
    return ((const int*)e)[grp];
  }
  static __device__ __forceinline__ float4 dec(Raw u) {
    floatx2 lo = __builtin_amdgcn_cvt_pk_f32_fp8(u, false);
    floatx2 hi = __builtin_amdgcn_cvt_pk_f32_fp8(u, true);
    return make_float4(lo[0], lo[1], hi[0], hi[1]);
  }
  static __device__ __forceinline__ float4 ld(const void* e, size_t grp) {
    return dec(ldraw(e, grp));
  }
  static __device__ __forceinline__ void st(void* e, size_t grp, float4 v) {
    int u = 0;
    u = __builtin_amdgcn_cvt_pk_fp8_f32(v.x, v.y, u, false);
    u = __builtin_amdgcn_cvt_pk_fp8_f32(v.z, v.w, u, true);
    ((int*)e)[grp] = u;
  }
  static __device__ __forceinline__ float ld1c(const void* e, size_t pos, int c) {
    const int dw = ((const int*)e)[pos * (DD / 4) + (c >> 2)];
    floatx2 lo = __builtin_amdgcn_cvt_pk_f32_fp8(dw, false);
    floatx2 hi = __builtin_amdgcn_cvt_pk_f32_fp8(dw, true);
    return (c & 2) ? ((c & 1) ? hi[1] : hi[0]) : ((c & 1) ? lo[1] : lo[0]);
  }
};

// ------------------------------------------------------------- init / CSR build
__global__ __launch_bounds__(256) void k_zero_init(int* __restrict__ cnt,
    float* __restrict__ stats) {
  int i = blockIdx.x * 256 + threadIdx.x;
  const int str = gridDim.x * 256;
  for (; i < NN; i += str) cnt[i] = 0;
  if (blockIdx.x == 0)
    for (int j = threadIdx.x; j < 768; j += 256) stats[j] = 0.f;
}

// pre-convert all 20 weight matrices to bf16 transposed [n][k] layout
__global__ __launch_bounds__(256) void k_prep(const float* __restrict__ WA,
    const float* __restrict__ WB, const float* __restrict__ WD,
    const float* __restrict__ WE, const float* __restrict__ WC,
    ushort* __restrict__ Wbf) {
  int gid = blockIdx.x * 256 + threadIdx.x;
  const int total = 20 * DD * DD;
  for (; gid < total; gid += gridDim.x * 256) {
    const int m = gid / (DD * DD), rem = gid - m * (DD * DD);
    const int n = rem / DD, k = rem - (rem / DD) * DD;
    const int l = m / 5, j = m - (m / 5) * 5;
    const float* src = (j == 0) ? WA : (j == 1) ? WB : (j == 2) ? WD : (j == 3) ? WE : WC;
    Wbf[gid] = f2bf(src[l * DD * DD + k * DD + n]);
  }
}

__global__ __launch_bounds__(256) void k_hist(const int* __restrict__ dst,
    int* __restrict__ cnt) {
  const int i = blockIdx.x * 256 + threadIdx.x;
  if (i < EE) atomicAdd(&cnt[dst[i]], 1);
}

__global__ __launch_bounds__(256) void k_scan(const int* __restrict__ cnt,
    int* __restrict__ rowptr, int* __restrict__ cursor) {
  __shared__ int part[256];
  const int t = threadIdx.x;
  const int CH = (NN + 255) / 256;
  const int lo = t * CH, hi = min((t + 1) * CH, NN);
  int s = 0;
  for (int i = lo; i < hi; i++) s += cnt[i];
  part[t] = s;
  __syncthreads();
  for (int off = 1; off < 256; off <<= 1) {
    int v = (t >= off) ? part[t - off] : 0;
    __syncthreads();
    part[t] += v;
    __syncthreads();
  }
  int base = (t == 0) ? 0 : part[t - 1];
  for (int i = lo; i < hi; i++) {
    rowptr[i] = base; cursor[i] = base; base += cnt[i];
  }
  if (t == 255) rowptr[NN] = base;
}

__global__ __launch_bounds__(256) void k_scatter(const int* __restrict__ src,
    const int* __restrict__ dst, int* __restrict__ cursor,
    int* __restrict__ perm, int* __restrict__ srcC, int* __restrict__ dstC) {
  const int i = blockIdx.x * 256 + threadIdx.x;
  if (i < EE) {
    const int d = dst[i];
    const int pos = atomicAdd(&cursor[d], 1);
    perm[pos] = i; srcC[pos] = src[i]; dstC[pos] = d;
  }
}

// ---------------------------------------------------------------- embeddings
__global__ __launch_bounds__(256) void k_embed_h(const float* __restrict__ h1,
    const float* __restrict__ h2, const float* __restrict__ z,
    const float* __restrict__ W, const float* __restrict__ b,
    ushort* __restrict__ h) {
  int idx = blockIdx.x * 256 + threadIdx.x;
  const int total = NN * DD;
  const int stride = gridDim.x * 256;
  for (; idx < total; idx += stride) {
    int n = idx / DD, c = idx - n * DD;
    float acc = b[c];
#pragma unroll
    for (int k = 0; k < 6; k++)  acc = fmaf(h1[n * 6 + k], W[k * DD + c], acc);
#pragma unroll
    for (int k = 0; k < 4; k++)  acc = fmaf(h2[n * 4 + k], W[(6 + k) * DD + c], acc);
#pragma unroll
    for (int k = 0; k < 16; k++) acc = fmaf(z[n * 16 + k], W[(10 + k) * DD + c], acc);
    h[idx] = f2bf(acc);
  }
}

template <int EZ>
__global__ __launch_bounds__(256) void k_embed_e(const float* __restrict__ ef,
    const float* __restrict__ W, const float* __restrict__ b,
    const int* __restrict__ perm, void* __restrict__ e) {
  int g = blockIdx.x * 256 + threadIdx.x;
  const int totalg = EE * (DD / 4);
  const int stride = gridDim.x * 256;
  for (; g < totalg; g += stride) {
    const int pos = g / 24, cg = (g - pos * 24) * 4;
    const int orig = perm[pos];
    const float f0 = ef[orig * 4], f1 = ef[orig * 4 + 1];
    const float f2 = ef[orig * 4 + 2], f3 = ef[orig * 4 + 3];
    float4 acc;
    acc.x = b[cg+0] + f0*W[cg+0] + f1*W[DD+cg+0] + f2*W[2*DD+cg+0] + f3*W[3*DD+cg+0];
    acc.y = b[cg+1] + f0*W[cg+1] + f1*W[DD+cg+1] + f2*W[2*DD+cg+1] + f3*W[3*DD+cg+1];
    acc.z = b[cg+2] + f0*W[cg+2] + f1*W[DD+cg+2] + f2*W[2*DD+cg+2] + f3*W[3*DD+cg+2];
    acc.w = b[cg+3] + f0*W[cg+3] + f1*W[DD+cg+3] + f2*W[2*DD+cg+3] + f3*W[3*DD+cg+3];
    EST<EZ>::st(e, g, acc);
  }
}

// ---------------- node GEMMs via MFMA: one block = 128 rows x all 4 matrices,
//                  with fused lazy h-update; weights pre-staged bf16 transposed.
template <int LAZY>
__global__ __launch_bounds__(256) void k_ngemm(ushort* __restrict__ h,
    const ushort* __restrict__ Wbf5,   // layer's 5-matrix bf16 block (A,B,D,E,C)
    const float* __restrict__ bAp, const float* __restrict__ bBp,
    const float* __restrict__ bDp, const float* __restrict__ bEp,
    ushort* __restrict__ oA, ushort* __restrict__ oB,
    ushort* __restrict__ oD, ushort* __restrict__ oE,
    const float* __restrict__ stats) {
  __shared__ __align__(16) ushort Wt[DD * LDA];
  __shared__ __align__(16) ushort At[128 * LDA];
  __shared__ float uscl[DD], ushf[DD];
  const int tid = threadIdx.x;
  if (LAZY && tid < DD) { uscl[tid] = stats[384 + tid]; ushf[tid] = stats[480 + tid]; }
  if (LAZY) __syncthreads();
  const int base = blockIdx.x * 128;
#pragma unroll
  for (int ii = 0; ii < 12; ii++) {
    const int i = ii * 256 + tid;
    const int r = i / 24, q = i - (i / 24) * 24;
    const int row = base + r;
    ushort4 a; a.x = 0; a.y = 0; a.z = 0; a.w = 0;
    if (row < NN) a = ((const ushort4*)h)[(size_t)row * 24 + q];
    if (LAZY && row < NN) {
      const ushort4 u = ((const ushort4*)oA)[(size_t)row * 24 + q];  // oA == hn
      const int c = q * 4;
      float f0 = bfu2f(a.x) + fmaxf(fmaf(bfu2f(u.x), uscl[c],     ushf[c]),     0.f);
      float f1 = bfu2f(a.y) + fmaxf(fmaf(bfu2f(u.y), uscl[c + 1], ushf[c + 1]), 0.f);
      float f2 = bfu2f(a.z) + fmaxf(fmaf(bfu2f(u.z), uscl[c + 2], ushf[c + 2]), 0.f);
      float f3 = bfu2f(a.w) + fmaxf(fmaf(bfu2f(u.w), uscl[c + 3], ushf[c + 3]), 0.f);
      a.x = f2bf(f0); a.y = f2bf(f1); a.z = f2bf(f2); a.w = f2bf(f3);
      ((ushort4*)h)[(size_t)row * 24 + q] = a;
    }
    *(ushort4*)&At[r * LDA + q * 4] = a;
  }
  const int w = tid >> 6, lane = tid & 63;
  const int lrow = lane & 15, lgrp = lane >> 4;
#pragma unroll
  for (int m = 0; m < 4; m++) {
    const float* bi = (m == 0) ? bAp : (m == 1) ? bBp : (m == 2) ? bDp : bEp;
    ushort* out     = (m == 0) ? oA  : (m == 1) ? oB  : (m == 2) ? oD  : oE;
    const ushort* Wm = Wbf5 + m * (DD * DD);
#pragma unroll
    for (int ii = 0; ii < 9; ii++) {
      const int i4 = ii * 256 + tid;     // 2304 ushort4 groups
      const int n = i4 / 24, k4 = i4 - (i4 / 24) * 24;
      *(ushort4*)&Wt[n * LDA + k4 * 4] = ((const ushort4*)Wm)[i4];
    }
    __syncthreads();
    f32x4 acc[2][6];
#pragma unroll
    for (int rt2 = 0; rt2 < 2; rt2++)
#pragma unroll
      for (int nt = 0; nt < 6; nt++) {
        acc[rt2][nt][0] = 0.f; acc[rt2][nt][1] = 0.f;
        acc[rt2][nt][2] = 0.f; acc[rt2][nt][3] = 0.f;
      }
#pragma unroll
    for (int rt2 = 0; rt2 < 2; rt2++) {
      const int rt = w * 2 + rt2;
#pragma unroll
      for (int kk = 0; kk < 3; kk++) {
        const bf16x8 af = *(const bf16x8*)&At[(rt * 16 + lrow) * LDA + kk * 32 + lgrp * 8];
#pragma unroll
        for (int nt = 0; nt < 6; nt++) {
          const bf16x8 bfr = *(const bf16x8*)&Wt[(nt * 16 + lrow) * LDA + kk * 32 + lgrp * 8];
          acc[rt2][nt] = __builtin_amdgcn_mfma_f32_16x16x32_bf16(af, bfr, acc[rt2][nt], 0, 0, 0);
        }
      }
    }
#pragma unroll
    for (int rt2 = 0; rt2 < 2; rt2++) {
      const int rt = w * 2 + rt2;
#pragma unroll
      for (int j = 0; j < 4; j++) {
        const int row = base + rt * 16 + lgrp * 4 + j;
        if (row < NN) {
#pragma unroll
          for (int nt = 0; nt < 6; nt++) {
            const int ch = nt * 16 + lrow;
            out[(size_t)row * DD + ch] = f2bf(acc[rt2][nt][j] + bi[ch]);
          }
        }
      }
    }
    __syncthreads();
  }
}

// ---------------- edge kernel with T14 async-stage (r9-proven).
// MODE 0: layer 0. MODE 1: apply pending BN-e update, write e back. MODE 2: no write-back.
template <int MODE, int EZE, int EZN>
__global__ __launch_bounds__(256) void k_edge(void* __restrict__ e,
    void* __restrict__ e_new,
    const ushort* __restrict__ WCbf, const float* __restrict__ bC,
    const ushort* __restrict__ Dh, const ushort* __restrict__ Eh,
    const int* __restrict__ srcC, const int* __restrict__ dstC,
    float* __restrict__ stats) {
  __shared__ __align__(16) ushort Wt[DD * LDA];
  __shared__ __align__(16) ushort At[64 * LDA];
  __shared__ float sred[2 * DD];
  __shared__ float escl[DD], eshl[DD];
  __shared__ int sidx_s[64], sidx_d[64];
  const int tid = threadIdx.x;
#pragma unroll
  for (int ii = 0; ii < 9; ii++) {
    const int i4 = ii * 256 + tid;
    const int n = i4 / 24, k4 = i4 - (i4 / 24) * 24;
    *(ushort4*)&Wt[n * LDA + k4 * 4] = ((const ushort4*)WCbf)[i4];
  }
  if (tid < 2 * DD) sred[tid] = 0.f;
  if (MODE >= 1 && tid < DD) { escl[tid] = stats[576 + tid]; eshl[tid] = stats[672 + tid]; }
  __syncthreads();
  const int w = tid >> 6, lane = tid & 63;
  const int lrow = lane & 15, lgrp = lane >> 4;
  const int qq0 = lane % 24;
  const int qq1 = (lane + 16) % 24;
  const int qq2 = (lane + 8) % 24;
  const float4 bc0 = *(const float4*)&bC[qq0 * 4];
  const float4 bc1 = *(const float4*)&bC[qq1 * 4];
  const float4 bc2 = *(const float4*)&bC[qq2 * 4];
  float sacc0[4] = {0,0,0,0}, sacc1[4] = {0,0,0,0}, sacc2[4] = {0,0,0,0};
  float qacc0[4] = {0,0,0,0}, qacc1[4] = {0,0,0,0}, qacc2[4] = {0,0,0,0};

  const int NT = EE / 64;   // 12500
  typename EST<EZE>::Raw pe[6];
  typename EST<EZN>::Raw pn[6];
  int ps = 0, pd = 0;
  {
    const size_t b24 = (size_t)blockIdx.x * 64 * 24;
#pragma unroll
    for (int ii = 0; ii < 6; ii++) {
      const int i = ii * 256 + tid;
      pe[ii] = EST<EZE>::ldraw(e, b24 + i);
      if (MODE >= 1) pn[ii] = EST<EZN>::ldraw(e_new, b24 + i);
    }
    if (tid < 64) {
      ps = srcC[blockIdx.x * 64 + tid];
      pd = dstC[blockIdx.x * 64 + tid];
    }
  }
  for (int t = blockIdx.x; t < NT; t += gridDim.x) {
    const size_t base = (size_t)t * 64;
    const size_t b24 = base * 24;
#pragma unroll
    for (int ii = 0; ii < 6; ii++) {
      const int i = ii * 256 + tid;
      const int r = i / 24, gq = i - (i / 24) * 24;
      float4 a = EST<EZE>::dec(pe[ii]);
      if (MODE >= 1) {
        const float4 d = EST<EZN>::dec(pn[ii]);
        const int c = gq * 4;
        a.x += fmaxf(fmaf(d.x, escl[c],     eshl[c]),     0.f);
        a.y += fmaxf(fmaf(d.y, escl[c + 1], eshl[c + 1]), 0.f);
        a.z += fmaxf(fmaf(d.z, escl[c + 2], eshl[c + 2]), 0.f);
        a.w += fmaxf(fmaf(d.w, escl[c + 3], eshl[c + 3]), 0.f);
        if (MODE == 1) EST<EZE>::st(e, b24 + i, a);
      }
      ushort4 o; o.x = f2bf(a.x); o.y = f2bf(a.y); o.z = f2bf(a.z); o.w = f2bf(a.w);
      *(ushort4*)&At[r * LDA + gq * 4] = o;
    }
    if (tid < 64) { sidx_s[tid] = ps; sidx_d[tid] = pd; }
    const int tn = t + gridDim.x;
    if (tn < NT) {
      const size_t bn = (size_t)tn * 64 * 24;
#pragma unroll
      for (int ii = 0; ii < 6; ii++) {
        const int i = ii * 256 + tid;
        pe[ii] = EST<EZE>::ldraw(e, bn + i);
        if (MODE >= 1) pn[ii] = EST<EZN>::ldraw(e_new, bn + i);
      }
      if (tid < 64) { ps = srcC[tn * 64 + tid]; pd = dstC[tn * 64 + tid]; }
    }
    __syncthreads();
    f32x4 acc[6];
#pragma unroll
    for (int nt = 0; nt < 6; nt++) { acc[nt][0]=0.f; acc[nt][1]=0.f; acc[nt][2]=0.f; acc[nt][3]=0.f; }
#pragma unroll
    for (int kk = 0; kk < 3; kk++) {
      const bf16x8 af = *(const bf16x8*)&At[(w * 16 + lrow) * LDA + kk * 32 + lgrp * 8];
#pragma unroll
      for (int nt = 0; nt < 6; nt++) {
        const bf16x8 bfr = *(const bf16x8*)&Wt[(nt * 16 + lrow) * LDA + kk * 32 + lgrp * 8];
        acc[nt] = __builtin_amdgcn_mfma_f32_16x16x32_bf16(af, bfr, acc[nt], 0, 0, 0);
      }
    }
#pragma unroll
    for (int j = 0; j < 4; j++) {
#pragma unroll
      for (int nt = 0; nt < 6; nt++) {
        At[(w * 16 + lgrp * 4 + j) * LDA + nt * 16 + lrow] = f2bf(acc[nt][j]);
      }
    }
#pragma unroll
    for (int it = 0; it < 6; it++) {
      const int idx = it * 64 + lane;
      const int r16 = idx / 24, gq = idx - (idx / 24) * 24;
      const int row = w * 16 + r16;
      const size_t pos = base + row;
      const int s = sidx_s[row], d2 = sidx_d[row];
      const ushort4 av = *(const ushort4*)&At[row * LDA + gq * 4];
      const ushort4 dv = *(const ushort4*)&Dh[(size_t)s * DD + gq * 4];
      const ushort4 ev = *(const ushort4*)&Eh[(size_t)d2 * DD + gq * 4];
      const float4 bc = (it % 3 == 0) ? bc0 : (it % 3 == 1) ? bc1 : bc2;
      float4 v;
      v.x = bfu2f(av.x) + bc.x + bfu2f(dv.x) + bfu2f(ev.x);
      v.y = bfu2f(av.y) + bc.y + bfu2f(dv.y) + bfu2f(ev.y);
      v.z = bfu2f(av.z) + bc.z + bfu2f(dv.z) + bfu2f(ev.z);
      v.w = bfu2f(av.w) + bc.w + bfu2f(dv.w) + bfu2f(ev.w);
      if (it % 3 == 0) {
        sacc0[0]+=v.x; sacc0[1]+=v.y; sacc0[2]+=v.z; sacc0[3]+=v.w;
        qacc0[0]+=v.x*v.x; qacc0[1]+=v.y*v.y; qacc0[2]+=v.z*v.z; qacc0[3]+=v.w*v.w;
      } else if (it % 3 == 1) {
        sacc1[0]+=v.x; sacc1[1]+=v.y; sacc1[2]+=v.z; sacc1[3]+=v.w;
        qacc1[0]+=v.x*v.x; qacc1[1]+=v.y*v.y; qacc1[2]+=v.z*v.z; qacc1[3]+=v.w*v.w;
      } else {
        sacc2[0]+=v.x; sacc2[1]+=v.y; sacc2[2]+=v.z; sacc2[3]+=v.w;
        qacc2[0]+=v.x*v.x; qacc2[1]+=v.y*v.y; qacc2[2]+=v.z*v.z; qacc2[3]+=v.w*v.w;
      }
      EST<EZN>::st(e_new, pos * 24 + gq, v);
    }
    __syncthreads();
  }
#pragma unroll
  for (int c = 0; c < 4; c++) {
    atomicAdd(&sred[qq0 * 4 + c], sacc0[c]);
    atomicAdd(&sred[DD + qq0 * 4 + c], qacc0[c]);
    atomicAdd(&sred[qq1 * 4 + c], sacc1[c]);
    atomicAdd(&sred[DD + qq1 * 4 + c], qacc1[c]);
    atomicAdd(&sred[qq2 * 4 + c], sacc2[c]);
    atomicAdd(&sred[DD + qq2 * 4 + c], qacc2[c]);
  }
  __syncthreads();
  if (tid < 2 * DD) atomicAdd(&stats[tid], sred[tid]);
}

// ---------------- CSR aggregation: 4-way unrolled degree loop, half-wave per node.
template <int EZN>
__global__ __launch_bounds__(256) void k_agg(const void* __restrict__ e_new,
    const int* __restrict__ srcC, const int* __restrict__ rowptr,
    const ushort* __restrict__ Bh, ushort* __restrict__ hn,
    float* __restrict__ stats) {
  __shared__ float sred[2 * DD];
  if (threadIdx.x < 2 * DD) sred[threadIdx.x] = 0.f;
  __syncthreads();
  const int hw = threadIdx.x >> 5, lane = threadIdx.x & 31;
  const int c0 = lane, c1 = lane + 32, c2 = lane + 64;
  float sa0 = 0, sa1 = 0, sa2 = 0, qa0 = 0, qa1 = 0, qa2 = 0;
  for (int n = blockIdx.x * 8 + hw; n < NN; n += gridDim.x * 8) {
    const int rs = rowptr[n], re = rowptr[n + 1];
    float n0 = 0, n1 = 0, n2 = 0, d0 = 0, d1 = 0, d2 = 0;
    int p = rs;
    for (; p + 4 <= re; p += 4) {
      float v0[4], v1[4], v2[4], b0[4], b1[4], b2[4];
#pragma unroll
      for (int j = 0; j < 4; j++) {
        const int s = srcC[p + j];
        v0[j] = EST<EZN>::ld1c(e_new, (size_t)(p + j), c0);
        v1[j] = EST<EZN>::ld1c(e_new, (size_t)(p + j), c1);
        v2[j] = EST<EZN>::ld1c(e_new, (size_t)(p + j), c2);
        const size_t sb = (size_t)s * DD;
        b0[j] = bfu2f(Bh[sb + c0]);
        b1[j] = bfu2f(Bh[sb + c1]);
        b2[j] = bfu2f(Bh[sb + c2]);
      }
#pragma unroll
      for (int j = 0; j < 4; j++) {
        const float g0 = 1.f / (1.f + __expf(-v0[j]));
        const float g1 = 1.f / (1.f + __expf(-v1[j]));
        const float g2 = 1.f / (1.f + __expf(-v2[j]));
        n0 += g0 * b0[j]; d0 += g0;
        n1 += g1 * b1[j]; d1 += g1;
        n2 += g2 * b2[j]; d2 += g2;
      }
    }
    for (; p < re; p++) {
      const int s = srcC[p];
      const float v0 = EST<EZN>::ld1c(e_new, (size_t)p, c0);
      const float v1 = EST<EZN>::ld1c(e_new, (size_t)p, c1);
      const float v2 = EST<EZN>::ld1c(e_new, (size_t)p, c2);
      const float g0 = 1.f / (1.f + __expf(-v0));
      const float g1 = 1.f / (1.f + __expf(-v1));
      const float g2 = 1.f / (1.f + __expf(-v2));
      const size_t sb = (size_t)s * DD;
      n0 += g0 * bfu2f(Bh[sb + c0]); d0 += g0;
      n1 += g1 * bfu2f(Bh[sb + c1]); d1 += g1;
      n2 += g2 * bfu2f(Bh[sb + c2]); d2 += g2;
    }
    const size_t hb = (size_t)n * DD;
    const float v0 = bfu2f(hn[hb + c0]) + n0 / (d0 + 1e-6f);
    const float v1 = bfu2f(hn[hb + c1]) + n1 / (d1 + 1e-6f);
    const float v2 = bfu2f(hn[hb + c2]) + n2 / (d2 + 1e-6f);
    hn[hb + c0] = f2bf(v0); hn[hb + c1] = f2bf(v1); hn[hb + c2] = f2bf(v2);
    sa0 += v0; qa0 += v0 * v0;
    sa1 += v1; qa1 += v1 * v1;
    sa2 += v2; qa2 += v2 * v2;
  }
  atomicAdd(&sred[c0], sa0); atomicAdd(&sred[c1], sa1); atomicAdd(&sred[c2], sa2);
  atomicAdd(&sred[DD + c0], qa0); atomicAdd(&sred[DD + c1], qa1); atomicAdd(&sred[DD + c2], qa2);
  __syncthreads();
  if (threadIdx.x < 2 * DD) atomicAdd(&stats[192 + threadIdx.x], sred[threadIdx.x]);
}

// ---------------- finalize BN stats -> scale/shift; zero raw slots for next layer
__global__ void k_finalize(float* __restrict__ stats,
    const float* __restrict__ g_h, const float* __restrict__ b_h,
    const float* __restrict__ g_e, const float* __restrict__ b_e) {
  const int c = threadIdx.x;
  if (c < DD) {
    const float mu_h = stats[192 + c] / (float)NN;
    const float var_h = stats[288 + c] / (float)NN - mu_h * mu_h;
    const float sc_h = g_h[c] * rsqrtf(var_h + 1e-5f);
    const float mu_e = stats[c] / (float)EE;
    const float var_e = stats[96 + c] / (float)EE - mu_e * mu_e;
    const float sc_e = g_e[c] * rsqrtf(var_e + 1e-5f);
    stats[384 + c] = sc_h;
    stats[480 + c] = b_h[c] - mu_h * sc_h;
    stats[576 + c] = sc_e;
    stats[672 + c] = b_e[c] - mu_e * sc_e;
    stats[c] = 0.f; stats[96 + c] = 0.f; stats[192 + c] = 0.f; stats[288 + c] = 0.f;
  }
}

// ------------------------- MLP head with fused final h-update (layer-3 BN-h)
__global__ __launch_bounds__(256) void k_head(const ushort* __restrict__ h,
    const ushort* __restrict__ hn, const float* __restrict__ stats,
    const float* __restrict__ W1, const float* __restrict__ b1,
    const float* __restrict__ W2, const float* __restrict__ b2,
    const float* __restrict__ ma, float* __restrict__ out) {
  __shared__ float W1l[DD * NHID];
  __shared__ float W2l[NHID * NOUT];
  __shared__ float hid[4][NHID];
  __shared__ float hrow[4][DD];
  __shared__ float uscl[DD], ushf[DD];
  for (int i = threadIdx.x; i < DD * NHID; i += 256) W1l[i] = W1[i];
  for (int i = threadIdx.x; i < NHID * NOUT; i += 256) W2l[i] = W2[i];
  if (threadIdx.x < DD) {
    uscl[threadIdx.x] = stats[384 + threadIdx.x];
    ushf[threadIdx.x] = stats[480 + threadIdx.x];
  }
  __syncthreads();
  const int w = threadIdx.x >> 6, lane = threadIdx.x & 63;
  for (int n = blockIdx.x * 4 + w; n < NN; n += gridDim.x * 4) {
    const ushort* hp = h + (size_t)n * DD;
    const ushort* up = hn + (size_t)n * DD;
    hrow[w][lane] = bfu2f(hp[lane])
        + fmaxf(fmaf(bfu2f(up[lane]), uscl[lane], ushf[lane]), 0.f);
    if (lane < DD - 64)
      hrow[w][64 + lane] = bfu2f(hp[64 + lane])
          + fmaxf(fmaf(bfu2f(up[64 + lane]), uscl[64 + lane], ushf[64 + lane]), 0.f);
    float a0 = b1[lane], a1 = b1[64 + lane];
    for (int k = 0; k < DD; k++) {
      const float x = hrow[w][k];
      a0 = fmaf(x, W1l[k * NHID + lane], a0);
      a1 = fmaf(x, W1l[k * NHID + 64 + lane], a1);
    }
    hid[w][lane] = fmaxf(a0, 0.f);
    hid[w][64 + lane] = fmaxf(a1, 0.f);
    if (lane < NOUT) {
      float o = b2[lane];
      for (int k = 0; k < NHID; k++) o = fmaf(hid[w][k], W2l[k * NOUT + lane], o);
      out[(size_t)n * NOUT + lane] = ma[n] * tanhf(o);
    }
  }
}

// ----------------------------------------------------------------------------
extern "C" void kernel_launch(void* const* d_in, const int* in_sizes, int n_in,
                              void* d_out, int out_size, void* d_ws, size_t ws_size,
                              hipStream_t stream) {
  const float* h1  = (const float*)d_in[0];
  const float* h2  = (const float*)d_in[1];
  const float* z   = (const float*)d_in[2];
  const float* ef  = (const float*)d_in[3];
  const float* ma  = (const float*)d_in[4];
  const float* Wh  = (const float*)d_in[5];
  const float* bh  = (const float*)d_in[6];
  const float* We  = (const float*)d_in[7];
  const float* be  = (const float*)d_in[8];
  const float* WA  = (const float*)d_in[9];
  const float* bA  = (const float*)d_in[10];
  const float* WB  = (const float*)d_in[11];
  const float* bB  = (const float*)d_in[12];
  const float* WC  = (const float*)d_in[13];
  const float* bC  = (const float*)d_in[14];
  const float* WD  = (const float*)d_in[15];
  const float* bD  = (const float*)d_in[16];
  const float* WE  = (const float*)d_in[17];
  const float* bE  = (const float*)d_in[18];
  const float* bn_h_g = (const float*)d_in[19];
  const float* bn_h_b = (const float*)d_in[20];
  const float* bn_e_g = (const float*)d_in[21];
  const float* bn_e_b = (const float*)d_in[22];
  const float* W1  = (const float*)d_in[23];
  const float* b1  = (const float*)d_in[24];
  const float* W2  = (const float*)d_in[25];
  const float* b2  = (const float*)d_in[26];
  const int*   src = (const int*)d_in[27];
  const int*   dst = (const int*)d_in[28];

  const size_t E_ELEMS = (size_t)EE * DD;
  const size_t N_ELEMS = (size_t)NN * DD;
  int tier;
  if (ws_size >= 455000000UL)      tier = 0;   // e bf16 + e_new bf16
  else if (ws_size >= 298000000UL) tier = 1;   // e fp8  + e_new bf16  (confirmed r5-r9)
  else                             tier = 2;   // e fp8  + e_new fp8
  const size_t esze = (tier == 0) ? 2 : 1;
  const size_t eszn = (tier <= 1) ? 2 : 1;

  char* p = (char*)d_ws;
  void* e     = (void*)p; p += E_ELEMS * esze;
  void* e_new = (void*)p; p += E_ELEMS * eszn;
  ushort* h   = (ushort*)p; p += N_ELEMS * 2;
  ushort* hn  = (ushort*)p; p += N_ELEMS * 2;
  ushort* Bhb = (ushort*)p; p += N_ELEMS * 2;
  ushort* Dhb = (ushort*)p; p += N_ELEMS * 2;
  ushort* Ehb = (ushort*)p; p += N_ELEMS * 2;
  int* cnt    = (int*)p; p += (size_t)NN * 4;
  int* rowptr = (int*)p; p += (size_t)(NN + 1) * 4;
  int* cursor = (int*)p; p += (size_t)NN * 4;
  int* perm   = (int*)p; p += (size_t)EE * 4;
  int* srcC   = (int*)p; p += (size_t)EE * 4;
  int* dstC   = (int*)p; p += (size_t)EE * 4;
  ushort* Wbf = (ushort*)p; p += (size_t)20 * DD * DD * 2;  // bf16 transposed weights
  float* stats = (float*)p;

  k_zero_init<<<64, 256, 0, stream>>>(cnt, stats);
  k_prep<<<720, 256, 0, stream>>>(WA, WB, WD, WE, WC, Wbf);
  k_hist<<<3125, 256, 0, stream>>>(dst, cnt);
  k_scan<<<1, 256, 0, stream>>>(cnt, rowptr, cursor);
  k_scatter<<<3125, 256, 0, stream>>>(src, dst, cursor, perm, srcC, dstC);
  k_embed_h<<<1024, 256, 0, stream>>>(h1, h2, z, Wh, bh, h);
  if (esze == 2) k_embed_e<2><<<2048, 256, 0, stream>>>(ef, We, be, perm, e);
  else           k_embed_e<1><<<2048, 256, 0, stream>>>(ef, We, be, perm, e);

  for (int l = 0; l < 4; l++) {
    const ushort* Wbf5 = Wbf + (size_t)l * 5 * DD * DD;
#define NG_ARGS h, Wbf5, bA + l*DD, bB + l*DD, bD + l*DD, bE + l*DD, \
    hn, Bhb, Dhb, Ehb, stats
    if (l == 0) k_ngemm<0><<<391, 256, 0, stream>>>(NG_ARGS);
    else        k_ngemm<1><<<391, 256, 0, stream>>>(NG_ARGS);
#undef NG_ARGS
    const ushort* WCbf = Wbf5 + 4 * DD * DD;
    const float* bCl = bC + l * DD;
#define EDGE_ARGS e, e_new, WCbf, bCl, Dhb, Ehb, srcC, dstC, stats
    if (tier == 0) {
      if (l == 0)      k_edge<0,2,2><<<1250, 256, 0, stream>>>(EDGE_ARGS);
      else if (l < 3)  k_edge<1,2,2><<<1250, 256, 0, stream>>>(EDGE_ARGS);
      else             k_edge<2,2,2><<<1250, 256, 0, stream>>>(EDGE_ARGS);
    } else if (tier == 1) {
      if (l == 0)      k_edge<0,1,2><<<1250, 256, 0, stream>>>(EDGE_ARGS);
      else if (l < 3)  k_edge<1,1,2><<<1250, 256, 0, stream>>>(EDGE_ARGS);
      else             k_edge<2,1,2><<<1250, 256, 0, stream>>>(EDGE_ARGS);
    } else {
      if (l == 0)      k_edge<0,1,1><<<1250, 256, 0, stream>>>(EDGE_ARGS);
      else if (l < 3)  k_edge<1,1,1><<<1250, 256, 0, stream>>>(EDGE_ARGS);
      else             k_edge<2,1,1><<<1250, 256, 0, stream>>>(EDGE_ARGS);
    }
#undef EDGE_ARGS
    if (eszn == 2) k_agg<2><<<2048, 256, 0, stream>>>(e_new, srcC, rowptr, Bhb, hn, stats);
    else           k_agg<1><<<2048, 256, 0, stream>>>(e_new, srcC, rowptr, Bhb, hn, stats);
    k_finalize<<<1, 128, 0, stream>>>(stats,
        bn_h_g + l * DD, bn_h_b + l * DD, bn_e_g + l * DD, bn_e_b + l * DD);
  }

  k_head<<<1024, 256, 0, stream>>>(h, hn, stats, W1, b1, W2, b2, ma, (float*)d_out);
}